// Round 13
// baseline (1010.895 us; speedup 1.0000x reference)
//
#include <hip/hip_runtime.h>

#define N_NODES 50000
#define N_PAD   50176            // 196 * 256 = 8 * 6272
#define N_EDGES 1600000
#define IN_CH   512
#define HID     256
#define OUT_CH  40
#define BN_EPS  1e-5f

#define HCHUNK  6272             // nodes per histogram chunk (8 chunks cover N_PAD)
#define NCHUNK  8
#define NSLICE  32               // edge slices; E/NSLICE = 50000 exactly

typedef _Float16 f16x8 __attribute__((ext_vector_type(8)));
typedef __attribute__((ext_vector_type(8))) unsigned short u16x8;
typedef __attribute__((ext_vector_type(4))) float f32x4;

__device__ __forceinline__ unsigned short f2h_us(float f) {
    _Float16 h = (_Float16)f;
    return __builtin_bit_cast(unsigned short, h);
}
__device__ __forceinline__ float h2f(unsigned short u) {
    return (float)__builtin_bit_cast(_Float16, u);
}
// split f into fp16 hi + fp16 lo (residual; exact subtraction in fp32)
__device__ __forceinline__ void f2h_split(float f, unsigned short& hi, unsigned short& lo) {
    _Float16 h = (_Float16)f;
    hi = __builtin_bit_cast(unsigned short, h);
    lo = f2h_us(f - (float)h);
}

// async global->LDS, 16B per lane; LDS dest is wave-uniform base + lane*16
__device__ __forceinline__ void gload_lds16(const void* gsrc, void* ldst) {
    __builtin_amdgcn_global_load_lds(
        (const __attribute__((address_space(1))) unsigned int*)gsrc,
        (__attribute__((address_space(3))) unsigned int*)ldst,
        16, 0, 0);
}

// ---------------- degree histograms via LDS privatization (no global atomics) ----------------
__global__ __launch_bounds__(256)
void hist_kernel(const int* __restrict__ row, const int* __restrict__ col,
                 int* __restrict__ part_row, int* __restrict__ part_col, int E) {
    __shared__ int hr[HCHUNK];
    __shared__ int hc[HCHUNK];
    int s = blockIdx.x;        // edge slice
    int c = blockIdx.y;        // node chunk
    int base = c * HCHUNK;
    int t = threadIdx.x;
    for (int i = t; i < HCHUNK; i += 256) { hr[i] = 0; hc[i] = 0; }
    __syncthreads();
    int e0 = s * (E / NSLICE), e1 = e0 + E / NSLICE;
    for (int e = e0 + t; e < e1; e += 256) {
        int r = row[e], cc = col[e];
        unsigned lr = (unsigned)(r - base);
        unsigned lc = (unsigned)(cc - base);
        if (lr < HCHUNK) atomicAdd(&hr[lr], 1);
        if (lc < HCHUNK) atomicAdd(&hc[lc], 1);
    }
    __syncthreads();
    int* pr = part_row + (size_t)s * N_PAD + base;
    int* pc = part_col + (size_t)s * N_PAD + base;
    for (int i = t; i < HCHUNK; i += 256) { pr[i] = hr[i]; pc[i] = hc[i]; }
}

// merge: deg_row -> dis; part_col counts -> per-node EXCLUSIVE prefix over slices; deg_col out
__global__ void merge_deg_kernel(const int* __restrict__ part_row, int* __restrict__ part_col,
                                 float* __restrict__ dis, int* __restrict__ deg_col, int n) {
    int i = blockIdx.x * blockDim.x + threadIdx.x;
    if (i < n) {
        int dr = 0;
        #pragma unroll
        for (int s = 0; s < NSLICE; ++s)
            dr += part_row[(size_t)s * N_PAD + i];
        int run = 0;
        #pragma unroll
        for (int s = 0; s < NSLICE; ++s) {
            int cnt = part_col[(size_t)s * N_PAD + i];
            part_col[(size_t)s * N_PAD + i] = run;   // exclusive prefix
            run += cnt;
        }
        dis[i] = rsqrtf((float)max(dr, 1));
        deg_col[i] = run;
    }
}

// ---------------- 3-phase exclusive prefix sum ----------------
__global__ void scan1_kernel(const int* __restrict__ deg, int* __restrict__ bsums, int n) {
    __shared__ int sd[256];
    int t = threadIdx.x;
    int i = blockIdx.x * 256 + t;
    sd[t] = (i < n) ? deg[i] : 0;
    __syncthreads();
    for (int o = 128; o > 0; o >>= 1) {
        if (t < o) sd[t] += sd[t + o];
        __syncthreads();
    }
    if (t == 0) bsums[blockIdx.x] = sd[0];
}

__global__ void scan2_kernel(int* __restrict__ bsums, int nb) {   // 1 block, 256 threads
    __shared__ int sd[256];
    int t = threadIdx.x;
    int v = (t < nb) ? bsums[t] : 0;
    sd[t] = v;
    __syncthreads();
    for (int o = 1; o < 256; o <<= 1) {
        int u = (t >= o) ? sd[t - o] : 0;
        __syncthreads();
        sd[t] += u;
        __syncthreads();
    }
    if (t < nb) bsums[t] = sd[t] - v;   // exclusive
}

__global__ void scan3_kernel(const int* __restrict__ deg, const int* __restrict__ bsums,
                             int* __restrict__ offsets, int n) {
    __shared__ int sd[256];
    int t = threadIdx.x;
    int i = blockIdx.x * 256 + t;
    sd[t] = (i < n) ? deg[i] : 0;
    __syncthreads();
    for (int o = 1; o < 256; o <<= 1) {
        int u = (t >= o) ? sd[t - o] : 0;
        __syncthreads();
        sd[t] += u;
        __syncthreads();
    }
    if (i < n) offsets[i + 1] = bsums[blockIdx.x] + sd[t];
    if (i == 0) offsets[0] = 0;
}

// ---------------- CSR fill, chunked: LDS cursors + precomputed slice offsets (no global atomics) ----
__global__ __launch_bounds__(256)
void fill_csr_kernel(const int* __restrict__ row, const int* __restrict__ col,
                     const float* __restrict__ dis, const int* __restrict__ offsets,
                     const int* __restrict__ part_col, int2* __restrict__ csr, int E) {
    __shared__ int cur[HCHUNK];
    int s = blockIdx.x;        // edge slice
    int c = blockIdx.y;        // node chunk
    int base = c * HCHUNK;
    int t = threadIdx.x;
    for (int i = t; i < HCHUNK; i += 256) cur[i] = 0;
    __syncthreads();
    int e0 = s * (E / NSLICE), e1 = e0 + E / NSLICE;
    for (int e = e0 + t; e < e1; e += 256) {
        int r = row[e], cc = col[e];
        unsigned lc = (unsigned)(cc - base);
        if (lc < HCHUNK) {
            int pos = atomicAdd(&cur[lc], 1);
            int idx = offsets[cc] + part_col[(size_t)s * N_PAD + cc] + pos;
            csr[idx] = make_int2(r, __float_as_int(dis[r] * dis[cc]));
        }
    }
}

// ---------------- x hi/lo split (fp16) ----------------
__global__ void split_x_kernel(const float* __restrict__ x, unsigned short* __restrict__ xhi,
                               unsigned short* __restrict__ xlo, int n4) {
    int i = blockIdx.x * blockDim.x + threadIdx.x;
    if (i < n4) {
        float4 v = ((const float4*)x)[i];
        float r[4] = {v.x, v.y, v.z, v.w};
        ushort4 hs, ls;
        unsigned short* hp = (unsigned short*)&hs;
        unsigned short* lp = (unsigned short*)&ls;
        #pragma unroll
        for (int j = 0; j < 4; ++j) f2h_split(r[j], hp[j], lp[j]);
        ((ushort4*)xhi)[i] = hs;
        ((ushort4*)xlo)[i] = ls;
    }
}

// ---------------- propagation (full-row fp16 gather, 8-deep MLP per half-wave) ----------------
__global__ void prop_kernel(const unsigned short* __restrict__ hsrc,
                            const int* __restrict__ offsets,
                            const int2* __restrict__ csr,
                            unsigned short* __restrict__ Ohi, unsigned short* __restrict__ Olo,
                            int n) {
    int node = blockIdx.x * 4 + (threadIdx.x >> 6);
    if (node >= n) return;
    int lane = threadIdx.x & 63;
    int half = lane >> 5;
    int cl   = lane & 31;           // 16B chunk id within the 512B row
    int beg = offsets[node], end = offsets[node + 1];
    float acc[8] = {0.f, 0.f, 0.f, 0.f, 0.f, 0.f, 0.f, 0.f};
    for (int i = beg; i < end; i += 16) {
        float w[8];
        int s[8];
        #pragma unroll
        for (int u = 0; u < 8; ++u) {
            int iu = i + 2 * u + half;
            int2 rec = csr[min(iu, end - 1)];
            w[u] = (iu < end) ? __int_as_float(rec.y) : 0.f;
            s[u] = rec.x;
        }
        u16x8 v[8];
        #pragma unroll
        for (int u = 0; u < 8; ++u)
            v[u] = *(const u16x8*)(hsrc + (size_t)s[u] * HID + cl * 8);
        #pragma unroll
        for (int u = 0; u < 8; ++u)
            #pragma unroll
            for (int j = 0; j < 8; ++j)
                acc[j] += w[u] * h2f((unsigned short)v[u][j]);
    }
    #pragma unroll
    for (int j = 0; j < 8; ++j) acc[j] += __shfl_xor(acc[j], 32);
    u16x8 ov;
    if (half == 0) {
        #pragma unroll
        for (int j = 0; j < 8; ++j) ov[j] = f2h_us(acc[j]);
        *(u16x8*)(Ohi + (size_t)node * HID + cl * 8) = ov;
    } else {
        #pragma unroll
        for (int j = 0; j < 8; ++j) {
            unsigned short h, l;
            f2h_split(acc[j], h, l);
            ov[j] = l;
        }
        *(u16x8*)(Olo + (size_t)node * HID + cl * 8) = ov;
    }
}

// ---------------- tiled transpose -> single fp16 plane: src[R][C] -> dst[C][R] ----------------
__global__ void transpose_half_kernel(const float* __restrict__ src,
                                      unsigned short* __restrict__ dhi, int R, int C) {
    __shared__ float tile[32][33];
    int c0 = blockIdx.x * 32, r0 = blockIdx.y * 32;
    int tx = threadIdx.x, ty = threadIdx.y;   // block (32, 8)
    #pragma unroll
    for (int i = 0; i < 32; i += 8) {
        int r = r0 + ty + i, c = c0 + tx;
        tile[ty + i][tx] = (r < R && c < C) ? src[(size_t)r * C + c] : 0.f;
    }
    __syncthreads();
    #pragma unroll
    for (int i = 0; i < 32; i += 8) {
        int c = c0 + ty + i, r = r0 + tx;
        if (c < C && r < R) dhi[(size_t)c * R + r] = f2h_us(tile[tx][ty + i]);
    }
}

// ---------------- MFMA GEMM (fp16): 256x128 tile, 8 waves, double-buffered 2-phase ----------------
#define GBM 256
#define GBN 128
#define GBK 32

// ACT: relu; OUTMODE: 0 = fp32 C, 1 = fp16 hi/lo pair; NC: column blocks; STATS: fused BN colstats
template<int ACT, int OUTMODE, int NC, int STATS>
__global__ __launch_bounds__(512)
void mfma_gemm_kernel(const unsigned short* __restrict__ A0h, const unsigned short* __restrict__ A0l,
                      const unsigned short* __restrict__ A1h, const unsigned short* __restrict__ A1l,
                      const unsigned short* __restrict__ A2h, const unsigned short* __restrict__ A2l,
                      const unsigned short* __restrict__ Wh,
                      const float* __restrict__ bvec,
                      float* __restrict__ C, unsigned short* __restrict__ Chi,
                      unsigned short* __restrict__ Clo,
                      float* __restrict__ bn_sums, float* __restrict__ bn_sumsq,
                      int M, int K, int seg, int Kout) {
    // [buf][kgroup(4)][row][8 f16]: A planes 16KB/buf, B plane 8KB/buf -> 80KB total (2 blocks/CU)
    __shared__ __attribute__((aligned(16))) unsigned short As_hi[2][4 * GBM * 8];
    __shared__ __attribute__((aligned(16))) unsigned short As_lo[2][4 * GBM * 8];
    __shared__ __attribute__((aligned(16))) unsigned short Bs_hi[2][4 * GBN * 8];

    int tid  = threadIdx.x;
    int lane = tid & 63;
    int w    = tid >> 6;                   // wave id 0..7
    int wm   = w & 3, wn = w >> 2;         // 4x2 waves, 64x64 output each
    int kg   = lane >> 4, lr = lane & 15;  // fragment lane decomposition
    int kgq  = w & 3, hf = w >> 2;         // staging role: kgroup + half

    int bid = blockIdx.x, p, c;
    if (NC == 2) {
        p = ((bid >> 4) << 3) + (bid & 7);
        c = (bid >> 3) & 1;
        if (p >= N_PAD / GBM) return;      // grid padded to multiple of 16
    } else { p = bid; c = 0; }
    int bm = p * GBM, bn = c * GBN;

    f32x4 acc[4][4];
    #pragma unroll
    for (int i = 0; i < 4; ++i)
        #pragma unroll
        for (int j = 0; j < 4; ++j)
            acc[i][j] = (f32x4){0.f, 0.f, 0.f, 0.f};

    // each wave issues exactly 5 global_load_lds per STAGE (4 A + 1 B)
    auto STAGE = [&](int buf, int k0) {
        const unsigned short *Aph, *Apl; int kl0;
        if (k0 < seg)          { Aph = A0h; Apl = A0l; kl0 = k0; }
        else if (k0 < 2 * seg) { Aph = A1h; Apl = A1l; kl0 = k0 - seg; }
        else                   { Aph = A2h; Apl = A2l; kl0 = k0 - 2 * seg; }
        const unsigned short* a_h = Aph + (size_t)(bm + hf * 128 + lane) * seg + kl0 + kgq * 8;
        const unsigned short* a_l = Apl + (size_t)(bm + hf * 128 + lane) * seg + kl0 + kgq * 8;
        const unsigned short* b_h = Wh + (size_t)(bn + hf * 64 + lane) * K + k0 + kgq * 8;
        size_t rA = (size_t)64 * seg;
        gload_lds16(a_h,      &As_hi[buf][(kgq * GBM + hf * 128)      * 8]);
        gload_lds16(a_h + rA, &As_hi[buf][(kgq * GBM + hf * 128 + 64) * 8]);
        gload_lds16(a_l,      &As_lo[buf][(kgq * GBM + hf * 128)      * 8]);
        gload_lds16(a_l + rA, &As_lo[buf][(kgq * GBM + hf * 128 + 64) * 8]);
        gload_lds16(b_h,      &Bs_hi[buf][(kgq * GBN + hf * 64)       * 8]);
    };

    int nt = K / GBK;
    STAGE(0, 0);
    asm volatile("s_waitcnt vmcnt(0)" ::: "memory");
    __builtin_amdgcn_s_barrier();
    __builtin_amdgcn_sched_barrier(0);

    for (int t = 0; t < nt; ++t) {
        int cur = t & 1;
        if (t + 1 < nt) STAGE(cur ^ 1, (t + 1) * GBK);   // overlaps this step's compute

        int abase = (kg * GBM + wm * 64 + lr) * 8;
        int bbase = (kg * GBN + wn * 64 + lr) * 8;
        f16x8 ah[4], al[4], bh[4];
        #pragma unroll
        for (int mf = 0; mf < 4; ++mf) {
            ah[mf] = *(const f16x8*)&As_hi[cur][abase + mf * 16 * 8];
            al[mf] = *(const f16x8*)&As_lo[cur][abase + mf * 16 * 8];
        }
        #pragma unroll
        for (int nf = 0; nf < 4; ++nf)
            bh[nf] = *(const f16x8*)&Bs_hi[cur][bbase + nf * 16 * 8];
        #pragma unroll
        for (int mf = 0; mf < 4; ++mf)
            #pragma unroll
            for (int nf = 0; nf < 4; ++nf) {
                acc[mf][nf] = __builtin_amdgcn_mfma_f32_16x16x32_f16(ah[mf], bh[nf], acc[mf][nf], 0, 0, 0);
                acc[mf][nf] = __builtin_amdgcn_mfma_f32_16x16x32_f16(al[mf], bh[nf], acc[mf][nf], 0, 0, 0);
            }

        asm volatile("s_waitcnt vmcnt(0)" ::: "memory");  // next tile landed
        __builtin_amdgcn_s_barrier();                     // all waves done reading buf cur
        __builtin_amdgcn_sched_barrier(0);
    }

    // ---- epilogue: C/D layout col = lane&15, row = (lane>>4)*4 + reg ----
    #pragma unroll
    for (int nf = 0; nf < 4; ++nf) {
        int col = bn + wn * 64 + nf * 16 + lr;
        if (col >= Kout) continue;
        float bv = bvec[col];
        float s1 = 0.f, s2 = 0.f;
        #pragma unroll
        for (int mf = 0; mf < 4; ++mf) {
            #pragma unroll
            for (int i = 0; i < 4; ++i) {
                int rw = bm + wm * 64 + mf * 16 + kg * 4 + i;
                if (rw < M) {
                    float v = acc[mf][nf][i] + bv;
                    if (ACT == 1) v = fmaxf(v, 0.f);
                    if (STATS) { s1 += v; s2 += v * v; }
                    if (OUTMODE == 0) {
                        C[(size_t)rw * Kout + col] = v;
                    } else {
                        unsigned short hs, ls;
                        f2h_split(v, hs, ls);
                        Chi[(size_t)rw * Kout + col] = hs;
                        Clo[(size_t)rw * Kout + col] = ls;
                    }
                }
            }
        }
        if (STATS) {
            s1 += __shfl_xor(s1, 16); s1 += __shfl_xor(s1, 32);
            s2 += __shfl_xor(s2, 16); s2 += __shfl_xor(s2, 32);
            if (kg == 0) {
                atomicAdd(&bn_sums[col], s1);
                atomicAdd(&bn_sumsq[col], s2);
            }
        }
    }
}

__global__ void bnrelu_kernel(const float* __restrict__ y, const float* __restrict__ sums,
                              const float* __restrict__ sumsq, const float* __restrict__ g,
                              const float* __restrict__ beta,
                              unsigned short* __restrict__ Hhi, unsigned short* __restrict__ Hlo,
                              int M) {
    int idx = blockIdx.x * blockDim.x + threadIdx.x;   // group of 4 channels
    if (idx < M * HID / 4) {
        int col0 = (idx * 4) & (HID - 1);
        float4 v = ((const float4*)y)[idx];
        float invM = 1.0f / (float)M;
        float r[4] = {v.x, v.y, v.z, v.w};
        ushort4 hs, ls;
        unsigned short* hp = (unsigned short*)&hs;
        unsigned short* lp = (unsigned short*)&ls;
        #pragma unroll
        for (int j = 0; j < 4; ++j) {
            int col = col0 + j;
            float mean = sums[col] * invM;
            float var  = fmaxf(sumsq[col] * invM - mean * mean, 0.f);
            float o = (r[j] - mean) * rsqrtf(var + BN_EPS) * g[col] + beta[col];
            o = fmaxf(o, 0.f);
            f2h_split(o, hp[j], lp[j]);
        }
        ((ushort4*)Hhi)[idx] = hs;
        ((ushort4*)Hlo)[idx] = ls;
    }
}

extern "C" void kernel_launch(void* const* d_in, const int* in_sizes, int n_in,
                              void* d_out, int out_size, void* d_ws, size_t ws_size,
                              hipStream_t stream) {
    const float* x      = (const float*)d_in[0];
    const int*   ei     = (const int*)d_in[1];
    const float* W_feat = (const float*)d_in[2];
    const float* b_feat = (const float*)d_in[3];
    const float* W0     = (const float*)d_in[4];
    const float* b0     = (const float*)d_in[5];
    const float* g0     = (const float*)d_in[6];
    const float* beta0  = (const float*)d_in[7];
    const float* W1     = (const float*)d_in[8];
    const float* b1     = (const float*)d_in[9];
    const float* g1     = (const float*)d_in[10];
    const float* beta1  = (const float*)d_in[11];
    const float* Wc     = (const float*)d_in[12];
    const float* bc     = (const float*)d_in[13];
    float* out = (float*)d_out;

    const int N = N_NODES, E = N_EDGES;
    const int* row = ei;
    const int* col = ei + E;

    // workspace carve-up
    char* ws = (char*)d_ws;
    size_t off = 0;
    auto alloc = [&](size_t bytes) -> void* {
        void* p = ws + off;
        off = (off + bytes + 255) & ~(size_t)255;
        return p;
    };
    int*   deg_col  = (int*)  alloc(N * 4);
    int*   offsets  = (int*)  alloc((N + 1) * 4);
    int*   bsums    = (int*)  alloc(256 * 4);
    float* dis      = (float*)alloc(N * 4);
    int*   part_row = (int*)  alloc((size_t)NSLICE * N_PAD * 4);
    int*   part_col = (int*)  alloc((size_t)NSLICE * N_PAD * 4);
    int2*  csr      = (int2*) alloc((size_t)E * 8);
    unsigned short* x_hi    = (unsigned short*)alloc((size_t)N_PAD * IN_CH * 2);
    unsigned short* x_lo    = (unsigned short*)alloc((size_t)N_PAD * IN_CH * 2);
    unsigned short* h_hi    = (unsigned short*)alloc((size_t)N_PAD * HID * 2);
    unsigned short* h_lo    = (unsigned short*)alloc((size_t)N_PAD * HID * 2);
    unsigned short* agg1_hi = (unsigned short*)alloc((size_t)N_PAD * HID * 2);
    unsigned short* agg1_lo = (unsigned short*)alloc((size_t)N_PAD * HID * 2);
    // lifetime aliasing: x_hi/x_lo are dead after the feat GEMM; reuse the region
    unsigned short* agg2_hi = x_hi;
    unsigned short* agg2_lo = x_hi + (size_t)N_PAD * HID;
    float*          y       = (float*)x_lo;
    float* sums     = (float*)alloc(HID * 4);
    float* sumsq    = (float*)alloc(HID * 4);
    unsigned short* WTf_hi = (unsigned short*)alloc((size_t)HID * IN_CH * 2);
    unsigned short* WT0_hi = (unsigned short*)alloc((size_t)HID * 3 * HID * 2);
    unsigned short* WT1_hi = (unsigned short*)alloc((size_t)HID * 3 * HID * 2);
    unsigned short* WTc_hi = (unsigned short*)alloc((size_t)128 * HID * 2);   // 40 rows padded to 128

    hipMemsetAsync(WTc_hi, 0, (size_t)128 * HID * 2, stream);

    // operand pre-splits (independent of CSR build)
    split_x_kernel<<<(N * IN_CH / 4 + 255) / 256, 256, 0, stream>>>(x, x_hi, x_lo, N * IN_CH / 4);
    dim3 tb(32, 8);
    transpose_half_kernel<<<dim3(HID / 32, IN_CH / 32), tb, 0, stream>>>(W_feat, WTf_hi, IN_CH, HID);
    transpose_half_kernel<<<dim3(HID / 32, 3 * HID / 32), tb, 0, stream>>>(W0, WT0_hi, 3 * HID, HID);
    transpose_half_kernel<<<dim3(HID / 32, 3 * HID / 32), tb, 0, stream>>>(W1, WT1_hi, 3 * HID, HID);
    transpose_half_kernel<<<dim3((OUT_CH + 31) / 32, HID / 32), tb, 0, stream>>>(Wc, WTc_hi, HID, OUT_CH);

    // degree histograms (LDS-privatized, atomic-free globally)
    hist_kernel<<<dim3(NSLICE, NCHUNK), 256, 0, stream>>>(row, col, part_row, part_col, E);
    merge_deg_kernel<<<(N + 255) / 256, 256, 0, stream>>>(part_row, part_col, dis, deg_col, N);

    const int NB_SCAN = (N + 255) / 256;   // 196
    scan1_kernel<<<NB_SCAN, 256, 0, stream>>>(deg_col, bsums, N);
    scan2_kernel<<<1, 256, 0, stream>>>(bsums, NB_SCAN);
    scan3_kernel<<<NB_SCAN, 256, 0, stream>>>(deg_col, bsums, offsets, N);
    // chunked fill: LDS cursors + per-(slice,node) offsets from hist prefix
    fill_csr_kernel<<<dim3(NSLICE, NCHUNK), 256, 0, stream>>>(row, col, dis, offsets,
                                                              part_col, csr, E);

    // NC=2 grids: 196 panels x 2 col-blocks, swizzle needs grid multiple of 16 -> 400 (guarded)
    const int G2 = 400;
    // h = relu(x @ W_feat + b_feat) -> fp16 hi/lo pair
    mfma_gemm_kernel<1, 1, 2, 0><<<G2, 512, 0, stream>>>(
        x_hi, x_lo, nullptr, nullptr, nullptr, nullptr, WTf_hi, b_feat,
        nullptr, h_hi, h_lo, nullptr, nullptr, N, IN_CH, IN_CH, HID);

    const unsigned short* WThs[2] = {WT0_hi, WT1_hi};
    const float* bs[2]    = {b0, b1};
    const float* gs[2]    = {g0, g1};
    const float* betas[2] = {beta0, beta1};
    int prop_grid = (N + 3) / 4;
    for (int layer = 0; layer < 2; ++layer) {
        prop_kernel<<<prop_grid, 256, 0, stream>>>(h_hi, offsets, csr, agg1_hi, agg1_lo, N);
        prop_kernel<<<prop_grid, 256, 0, stream>>>(agg1_hi, offsets, csr, agg2_hi, agg2_lo, N);
        hipMemsetAsync(sums, 0, HID * 4, stream);
        hipMemsetAsync(sumsq, 0, HID * 4, stream);
        mfma_gemm_kernel<0, 0, 2, 1><<<G2, 512, 0, stream>>>(
            h_hi, h_lo, agg1_hi, agg1_lo, agg2_hi, agg2_lo, WThs[layer], bs[layer],
            y, nullptr, nullptr, sums, sumsq, N, 3 * HID, HID, HID);
        bnrelu_kernel<<<(N * HID / 4 + 255) / 256, 256, 0, stream>>>(y, sums, sumsq, gs[layer],
                                                                     betas[layer], h_hi, h_lo, N);
    }

    mfma_gemm_kernel<0, 0, 1, 0><<<N_PAD / GBM, 512, 0, stream>>>(
        h_hi, h_lo, nullptr, nullptr, nullptr, nullptr, WTc_hi, bc,
        out, nullptr, nullptr, nullptr, nullptr, N, HID, HID, OUT_CH);
}

// Round 14
// 868.926 us; speedup vs baseline: 1.1634x; 1.1634x over previous
//
#include <hip/hip_runtime.h>

#define N_NODES 50000
#define N_PAD   50176            // 196 * 256 = 8 * 6272
#define N_EDGES 1600000
#define IN_CH   512
#define HID     256
#define OUT_CH  40
#define BN_EPS  1e-5f

#define HCHUNK  6272             // nodes per histogram chunk (8 chunks cover N_PAD)
#define NCHUNK  8
#define NSLICE  32               // edge slices; E/NSLICE = 50000 exactly
#define HTHREADS 1024            // threads for hist/fill blocks (occupancy: 16 waves/block)

typedef _Float16 f16x8 __attribute__((ext_vector_type(8)));
typedef __attribute__((ext_vector_type(8))) unsigned short u16x8;
typedef __attribute__((ext_vector_type(4))) float f32x4;

__device__ __forceinline__ unsigned short f2h_us(float f) {
    _Float16 h = (_Float16)f;
    return __builtin_bit_cast(unsigned short, h);
}
__device__ __forceinline__ float h2f(unsigned short u) {
    return (float)__builtin_bit_cast(_Float16, u);
}
// split f into fp16 hi + fp16 lo (residual; exact subtraction in fp32)
__device__ __forceinline__ void f2h_split(float f, unsigned short& hi, unsigned short& lo) {
    _Float16 h = (_Float16)f;
    hi = __builtin_bit_cast(unsigned short, h);
    lo = f2h_us(f - (float)h);
}

// async global->LDS, 16B per lane; LDS dest is wave-uniform base + lane*16
__device__ __forceinline__ void gload_lds16(const void* gsrc, void* ldst) {
    __builtin_amdgcn_global_load_lds(
        (const __attribute__((address_space(1))) unsigned int*)gsrc,
        (__attribute__((address_space(3))) unsigned int*)ldst,
        16, 0, 0);
}

// ---------------- degree histograms via LDS privatization (no global atomics) ----------------
__global__ __launch_bounds__(HTHREADS)
void hist_kernel(const int* __restrict__ row, const int* __restrict__ col,
                 int* __restrict__ part_row, int* __restrict__ part_col, int E) {
    __shared__ int hr[HCHUNK];
    __shared__ int hc[HCHUNK];
    int s = blockIdx.x;        // edge slice
    int c = blockIdx.y;        // node chunk
    int base = c * HCHUNK;
    int t = threadIdx.x;
    for (int i = t; i < HCHUNK; i += HTHREADS) { hr[i] = 0; hc[i] = 0; }
    __syncthreads();
    int e0 = s * (E / NSLICE), e1 = e0 + E / NSLICE;
    for (int e = e0 + t; e < e1; e += HTHREADS) {
        int r = row[e], cc = col[e];
        unsigned lr = (unsigned)(r - base);
        unsigned lc = (unsigned)(cc - base);
        if (lr < HCHUNK) atomicAdd(&hr[lr], 1);
        if (lc < HCHUNK) atomicAdd(&hc[lc], 1);
    }
    __syncthreads();
    int* pr = part_row + (size_t)s * N_PAD + base;
    int* pc = part_col + (size_t)s * N_PAD + base;
    for (int i = t; i < HCHUNK; i += HTHREADS) { pr[i] = hr[i]; pc[i] = hc[i]; }
}

// merge: deg_row -> dis; part_col counts -> per-node EXCLUSIVE prefix over slices; deg_col out
__global__ void merge_deg_kernel(const int* __restrict__ part_row, int* __restrict__ part_col,
                                 float* __restrict__ dis, int* __restrict__ deg_col, int n) {
    int i = blockIdx.x * blockDim.x + threadIdx.x;
    if (i < n) {
        int dr = 0;
        #pragma unroll
        for (int s = 0; s < NSLICE; ++s)
            dr += part_row[(size_t)s * N_PAD + i];
        int run = 0;
        #pragma unroll
        for (int s = 0; s < NSLICE; ++s) {
            int cnt = part_col[(size_t)s * N_PAD + i];
            part_col[(size_t)s * N_PAD + i] = run;   // exclusive prefix
            run += cnt;
        }
        dis[i] = rsqrtf((float)max(dr, 1));
        deg_col[i] = run;
    }
}

// ---------------- 3-phase exclusive prefix sum ----------------
__global__ void scan1_kernel(const int* __restrict__ deg, int* __restrict__ bsums, int n) {
    __shared__ int sd[256];
    int t = threadIdx.x;
    int i = blockIdx.x * 256 + t;
    sd[t] = (i < n) ? deg[i] : 0;
    __syncthreads();
    for (int o = 128; o > 0; o >>= 1) {
        if (t < o) sd[t] += sd[t + o];
        __syncthreads();
    }
    if (t == 0) bsums[blockIdx.x] = sd[0];
}

__global__ void scan2_kernel(int* __restrict__ bsums, int nb) {   // 1 block, 256 threads
    __shared__ int sd[256];
    int t = threadIdx.x;
    int v = (t < nb) ? bsums[t] : 0;
    sd[t] = v;
    __syncthreads();
    for (int o = 1; o < 256; o <<= 1) {
        int u = (t >= o) ? sd[t - o] : 0;
        __syncthreads();
        sd[t] += u;
        __syncthreads();
    }
    if (t < nb) bsums[t] = sd[t] - v;   // exclusive
}

__global__ void scan3_kernel(const int* __restrict__ deg, const int* __restrict__ bsums,
                             int* __restrict__ offsets, int n) {
    __shared__ int sd[256];
    int t = threadIdx.x;
    int i = blockIdx.x * 256 + t;
    sd[t] = (i < n) ? deg[i] : 0;
    __syncthreads();
    for (int o = 1; o < 256; o <<= 1) {
        int u = (t >= o) ? sd[t - o] : 0;
        __syncthreads();
        sd[t] += u;
        __syncthreads();
    }
    if (i < n) offsets[i + 1] = bsums[blockIdx.x] + sd[t];
    if (i == 0) offsets[0] = 0;
}

// ---------------- CSR fill, chunked: LDS cursors + precomputed slice offsets (no global atomics) ----
__global__ __launch_bounds__(HTHREADS)
void fill_csr_kernel(const int* __restrict__ row, const int* __restrict__ col,
                     const float* __restrict__ dis, const int* __restrict__ offsets,
                     const int* __restrict__ part_col, int2* __restrict__ csr, int E) {
    __shared__ int cur[HCHUNK];
    int s = blockIdx.x;        // edge slice
    int c = blockIdx.y;        // node chunk
    int base = c * HCHUNK;
    int t = threadIdx.x;
    for (int i = t; i < HCHUNK; i += HTHREADS) cur[i] = 0;
    __syncthreads();
    int e0 = s * (E / NSLICE), e1 = e0 + E / NSLICE;
    for (int e = e0 + t; e < e1; e += HTHREADS) {
        int r = row[e], cc = col[e];
        unsigned lc = (unsigned)(cc - base);
        if (lc < HCHUNK) {
            int pos = atomicAdd(&cur[lc], 1);
            int idx = offsets[cc] + part_col[(size_t)s * N_PAD + cc] + pos;
            csr[idx] = make_int2(r, __float_as_int(dis[r] * dis[cc]));
        }
    }
}

// ---------------- x hi/lo split (fp16) ----------------
__global__ void split_x_kernel(const float* __restrict__ x, unsigned short* __restrict__ xhi,
                               unsigned short* __restrict__ xlo, int n4) {
    int i = blockIdx.x * blockDim.x + threadIdx.x;
    if (i < n4) {
        float4 v = ((const float4*)x)[i];
        float r[4] = {v.x, v.y, v.z, v.w};
        ushort4 hs, ls;
        unsigned short* hp = (unsigned short*)&hs;
        unsigned short* lp = (unsigned short*)&ls;
        #pragma unroll
        for (int j = 0; j < 4; ++j) f2h_split(r[j], hp[j], lp[j]);
        ((ushort4*)xhi)[i] = hs;
        ((ushort4*)xlo)[i] = ls;
    }
}

// ---------------- propagation (full-row fp16 gather, 8-deep MLP per half-wave) ----------------
__global__ void prop_kernel(const unsigned short* __restrict__ hsrc,
                            const int* __restrict__ offsets,
                            const int2* __restrict__ csr,
                            unsigned short* __restrict__ Ohi, unsigned short* __restrict__ Olo,
                            int n) {
    int node = blockIdx.x * 4 + (threadIdx.x >> 6);
    if (node >= n) return;
    int lane = threadIdx.x & 63;
    int half = lane >> 5;
    int cl   = lane & 31;           // 16B chunk id within the 512B row
    int beg = offsets[node], end = offsets[node + 1];
    float acc[8] = {0.f, 0.f, 0.f, 0.f, 0.f, 0.f, 0.f, 0.f};
    for (int i = beg; i < end; i += 16) {
        float w[8];
        int s[8];
        #pragma unroll
        for (int u = 0; u < 8; ++u) {
            int iu = i + 2 * u + half;
            int2 rec = csr[min(iu, end - 1)];
            w[u] = (iu < end) ? __int_as_float(rec.y) : 0.f;
            s[u] = rec.x;
        }
        u16x8 v[8];
        #pragma unroll
        for (int u = 0; u < 8; ++u)
            v[u] = *(const u16x8*)(hsrc + (size_t)s[u] * HID + cl * 8);
        #pragma unroll
        for (int u = 0; u < 8; ++u)
            #pragma unroll
            for (int j = 0; j < 8; ++j)
                acc[j] += w[u] * h2f((unsigned short)v[u][j]);
    }
    #pragma unroll
    for (int j = 0; j < 8; ++j) acc[j] += __shfl_xor(acc[j], 32);
    u16x8 ov;
    if (half == 0) {
        #pragma unroll
        for (int j = 0; j < 8; ++j) ov[j] = f2h_us(acc[j]);
        *(u16x8*)(Ohi + (size_t)node * HID + cl * 8) = ov;
    } else {
        #pragma unroll
        for (int j = 0; j < 8; ++j) {
            unsigned short h, l;
            f2h_split(acc[j], h, l);
            ov[j] = l;
        }
        *(u16x8*)(Olo + (size_t)node * HID + cl * 8) = ov;
    }
}

// ---------------- tiled transpose -> single fp16 plane: src[R][C] -> dst[C][R] ----------------
__global__ void transpose_half_kernel(const float* __restrict__ src,
                                      unsigned short* __restrict__ dhi, int R, int C) {
    __shared__ float tile[32][33];
    int c0 = blockIdx.x * 32, r0 = blockIdx.y * 32;
    int tx = threadIdx.x, ty = threadIdx.y;   // block (32, 8)
    #pragma unroll
    for (int i = 0; i < 32; i += 8) {
        int r = r0 + ty + i, c = c0 + tx;
        tile[ty + i][tx] = (r < R && c < C) ? src[(size_t)r * C + c] : 0.f;
    }
    __syncthreads();
    #pragma unroll
    for (int i = 0; i < 32; i += 8) {
        int c = c0 + ty + i, r = r0 + tx;
        if (c < C && r < R) dhi[(size_t)c * R + r] = f2h_us(tile[tx][ty + i]);
    }
}

// ---------------- MFMA GEMM (fp16): 256x128 tile, 8 waves, double-buffered 2-phase ----------------
#define GBM 256
#define GBN 128
#define GBK 32

// ACT: relu; OUTMODE: 0 = fp32 C, 1 = fp16 hi/lo pair; NC: column blocks; STATS: fused BN colstats
template<int ACT, int OUTMODE, int NC, int STATS>
__global__ __launch_bounds__(512)
void mfma_gemm_kernel(const unsigned short* __restrict__ A0h, const unsigned short* __restrict__ A0l,
                      const unsigned short* __restrict__ A1h, const unsigned short* __restrict__ A1l,
                      const unsigned short* __restrict__ A2h, const unsigned short* __restrict__ A2l,
                      const unsigned short* __restrict__ Wh,
                      const float* __restrict__ bvec,
                      float* __restrict__ C, unsigned short* __restrict__ Chi,
                      unsigned short* __restrict__ Clo,
                      float* __restrict__ bn_sums, float* __restrict__ bn_sumsq,
                      int M, int K, int seg, int Kout) {
    // [buf][kgroup(4)][row][8 f16]: A planes 16KB/buf, B plane 8KB/buf -> 80KB total (2 blocks/CU)
    __shared__ __attribute__((aligned(16))) unsigned short As_hi[2][4 * GBM * 8];
    __shared__ __attribute__((aligned(16))) unsigned short As_lo[2][4 * GBM * 8];
    __shared__ __attribute__((aligned(16))) unsigned short Bs_hi[2][4 * GBN * 8];

    int tid  = threadIdx.x;
    int lane = tid & 63;
    int w    = tid >> 6;                   // wave id 0..7
    int wm   = w & 3, wn = w >> 2;         // 4x2 waves, 64x64 output each
    int kg   = lane >> 4, lr = lane & 15;  // fragment lane decomposition
    int kgq  = w & 3, hf = w >> 2;         // staging role: kgroup + half

    int bid = blockIdx.x, p, c;
    if (NC == 2) {
        p = ((bid >> 4) << 3) + (bid & 7);
        c = (bid >> 3) & 1;
        if (p >= N_PAD / GBM) return;      // grid padded to multiple of 16
    } else { p = bid; c = 0; }
    int bm = p * GBM, bn = c * GBN;

    f32x4 acc[4][4];
    #pragma unroll
    for (int i = 0; i < 4; ++i)
        #pragma unroll
        for (int j = 0; j < 4; ++j)
            acc[i][j] = (f32x4){0.f, 0.f, 0.f, 0.f};

    // each wave issues exactly 5 global_load_lds per STAGE (4 A + 1 B)
    auto STAGE = [&](int buf, int k0) {
        const unsigned short *Aph, *Apl; int kl0;
        if (k0 < seg)          { Aph = A0h; Apl = A0l; kl0 = k0; }
        else if (k0 < 2 * seg) { Aph = A1h; Apl = A1l; kl0 = k0 - seg; }
        else                   { Aph = A2h; Apl = A2l; kl0 = k0 - 2 * seg; }
        const unsigned short* a_h = Aph + (size_t)(bm + hf * 128 + lane) * seg + kl0 + kgq * 8;
        const unsigned short* a_l = Apl + (size_t)(bm + hf * 128 + lane) * seg + kl0 + kgq * 8;
        const unsigned short* b_h = Wh + (size_t)(bn + hf * 64 + lane) * K + k0 + kgq * 8;
        size_t rA = (size_t)64 * seg;
        gload_lds16(a_h,      &As_hi[buf][(kgq * GBM + hf * 128)      * 8]);
        gload_lds16(a_h + rA, &As_hi[buf][(kgq * GBM + hf * 128 + 64) * 8]);
        gload_lds16(a_l,      &As_lo[buf][(kgq * GBM + hf * 128)      * 8]);
        gload_lds16(a_l + rA, &As_lo[buf][(kgq * GBM + hf * 128 + 64) * 8]);
        gload_lds16(b_h,      &Bs_hi[buf][(kgq * GBN + hf * 64)       * 8]);
    };

    int nt = K / GBK;
    STAGE(0, 0);
    asm volatile("s_waitcnt vmcnt(0)" ::: "memory");
    __builtin_amdgcn_s_barrier();
    __builtin_amdgcn_sched_barrier(0);

    for (int t = 0; t < nt; ++t) {
        int cur = t & 1;
        if (t + 1 < nt) STAGE(cur ^ 1, (t + 1) * GBK);   // overlaps this step's compute

        int abase = (kg * GBM + wm * 64 + lr) * 8;
        int bbase = (kg * GBN + wn * 64 + lr) * 8;
        f16x8 ah[4], al[4], bh[4];
        #pragma unroll
        for (int mf = 0; mf < 4; ++mf) {
            ah[mf] = *(const f16x8*)&As_hi[cur][abase + mf * 16 * 8];
            al[mf] = *(const f16x8*)&As_lo[cur][abase + mf * 16 * 8];
        }
        #pragma unroll
        for (int nf = 0; nf < 4; ++nf)
            bh[nf] = *(const f16x8*)&Bs_hi[cur][bbase + nf * 16 * 8];
        #pragma unroll
        for (int mf = 0; mf < 4; ++mf)
            #pragma unroll
            for (int nf = 0; nf < 4; ++nf) {
                acc[mf][nf] = __builtin_amdgcn_mfma_f32_16x16x32_f16(ah[mf], bh[nf], acc[mf][nf], 0, 0, 0);
                acc[mf][nf] = __builtin_amdgcn_mfma_f32_16x16x32_f16(al[mf], bh[nf], acc[mf][nf], 0, 0, 0);
            }

        asm volatile("s_waitcnt vmcnt(0)" ::: "memory");  // next tile landed
        __builtin_amdgcn_s_barrier();                     // all waves done reading buf cur
        __builtin_amdgcn_sched_barrier(0);
    }

    // ---- epilogue: C/D layout col = lane&15, row = (lane>>4)*4 + reg ----
    #pragma unroll
    for (int nf = 0; nf < 4; ++nf) {
        int col = bn + wn * 64 + nf * 16 + lr;
        if (col >= Kout) continue;
        float bv = bvec[col];
        float s1 = 0.f, s2 = 0.f;
        #pragma unroll
        for (int mf = 0; mf < 4; ++mf) {
            #pragma unroll
            for (int i = 0; i < 4; ++i) {
                int rw = bm + wm * 64 + mf * 16 + kg * 4 + i;
                if (rw < M) {
                    float v = acc[mf][nf][i] + bv;
                    if (ACT == 1) v = fmaxf(v, 0.f);
                    if (STATS) { s1 += v; s2 += v * v; }
                    if (OUTMODE == 0) {
                        C[(size_t)rw * Kout + col] = v;
                    } else {
                        unsigned short hs, ls;
                        f2h_split(v, hs, ls);
                        Chi[(size_t)rw * Kout + col] = hs;
                        Clo[(size_t)rw * Kout + col] = ls;
                    }
                }
            }
        }
        if (STATS) {
            s1 += __shfl_xor(s1, 16); s1 += __shfl_xor(s1, 32);
            s2 += __shfl_xor(s2, 16); s2 += __shfl_xor(s2, 32);
            if (kg == 0) {
                atomicAdd(&bn_sums[col], s1);
                atomicAdd(&bn_sumsq[col], s2);
            }
        }
    }
}

__global__ void bnrelu_kernel(const float* __restrict__ y, const float* __restrict__ sums,
                              const float* __restrict__ sumsq, const float* __restrict__ g,
                              const float* __restrict__ beta,
                              unsigned short* __restrict__ Hhi, unsigned short* __restrict__ Hlo,
                              int M) {
    int idx = blockIdx.x * blockDim.x + threadIdx.x;   // group of 4 channels
    if (idx < M * HID / 4) {
        int col0 = (idx * 4) & (HID - 1);
        float4 v = ((const float4*)y)[idx];
        float invM = 1.0f / (float)M;
        float r[4] = {v.x, v.y, v.z, v.w};
        ushort4 hs, ls;
        unsigned short* hp = (unsigned short*)&hs;
        unsigned short* lp = (unsigned short*)&ls;
        #pragma unroll
        for (int j = 0; j < 4; ++j) {
            int col = col0 + j;
            float mean = sums[col] * invM;
            float var  = fmaxf(sumsq[col] * invM - mean * mean, 0.f);
            float o = (r[j] - mean) * rsqrtf(var + BN_EPS) * g[col] + beta[col];
            o = fmaxf(o, 0.f);
            f2h_split(o, hp[j], lp[j]);
        }
        ((ushort4*)Hhi)[idx] = hs;
        ((ushort4*)Hlo)[idx] = ls;
    }
}

extern "C" void kernel_launch(void* const* d_in, const int* in_sizes, int n_in,
                              void* d_out, int out_size, void* d_ws, size_t ws_size,
                              hipStream_t stream) {
    const float* x      = (const float*)d_in[0];
    const int*   ei     = (const int*)d_in[1];
    const float* W_feat = (const float*)d_in[2];
    const float* b_feat = (const float*)d_in[3];
    const float* W0     = (const float*)d_in[4];
    const float* b0     = (const float*)d_in[5];
    const float* g0     = (const float*)d_in[6];
    const float* beta0  = (const float*)d_in[7];
    const float* W1     = (const float*)d_in[8];
    const float* b1     = (const float*)d_in[9];
    const float* g1     = (const float*)d_in[10];
    const float* beta1  = (const float*)d_in[11];
    const float* Wc     = (const float*)d_in[12];
    const float* bc     = (const float*)d_in[13];
    float* out = (float*)d_out;

    const int N = N_NODES, E = N_EDGES;
    const int* row = ei;
    const int* col = ei + E;

    // workspace carve-up
    char* ws = (char*)d_ws;
    size_t off = 0;
    auto alloc = [&](size_t bytes) -> void* {
        void* p = ws + off;
        off = (off + bytes + 255) & ~(size_t)255;
        return p;
    };
    int*   deg_col  = (int*)  alloc(N * 4);
    int*   offsets  = (int*)  alloc((N + 1) * 4);
    int*   bsums    = (int*)  alloc(256 * 4);
    float* dis      = (float*)alloc(N * 4);
    int*   part_row = (int*)  alloc((size_t)NSLICE * N_PAD * 4);
    int*   part_col = (int*)  alloc((size_t)NSLICE * N_PAD * 4);
    int2*  csr      = (int2*) alloc((size_t)E * 8);
    unsigned short* x_hi    = (unsigned short*)alloc((size_t)N_PAD * IN_CH * 2);
    unsigned short* x_lo    = (unsigned short*)alloc((size_t)N_PAD * IN_CH * 2);
    unsigned short* h_hi    = (unsigned short*)alloc((size_t)N_PAD * HID * 2);
    unsigned short* h_lo    = (unsigned short*)alloc((size_t)N_PAD * HID * 2);
    unsigned short* agg1_hi = (unsigned short*)alloc((size_t)N_PAD * HID * 2);
    unsigned short* agg1_lo = (unsigned short*)alloc((size_t)N_PAD * HID * 2);
    // lifetime aliasing: x_hi/x_lo are dead after the feat GEMM; reuse the region
    unsigned short* agg2_hi = x_hi;
    unsigned short* agg2_lo = x_hi + (size_t)N_PAD * HID;
    float*          y       = (float*)x_lo;
    float* sums     = (float*)alloc(HID * 4);
    float* sumsq    = (float*)alloc(HID * 4);
    unsigned short* WTf_hi = (unsigned short*)alloc((size_t)HID * IN_CH * 2);
    unsigned short* WT0_hi = (unsigned short*)alloc((size_t)HID * 3 * HID * 2);
    unsigned short* WT1_hi = (unsigned short*)alloc((size_t)HID * 3 * HID * 2);
    unsigned short* WTc_hi = (unsigned short*)alloc((size_t)128 * HID * 2);   // 40 rows padded to 128

    hipMemsetAsync(WTc_hi, 0, (size_t)128 * HID * 2, stream);

    // operand pre-splits (independent of CSR build)
    split_x_kernel<<<(N * IN_CH / 4 + 255) / 256, 256, 0, stream>>>(x, x_hi, x_lo, N * IN_CH / 4);
    dim3 tb(32, 8);
    transpose_half_kernel<<<dim3(HID / 32, IN_CH / 32), tb, 0, stream>>>(W_feat, WTf_hi, IN_CH, HID);
    transpose_half_kernel<<<dim3(HID / 32, 3 * HID / 32), tb, 0, stream>>>(W0, WT0_hi, 3 * HID, HID);
    transpose_half_kernel<<<dim3(HID / 32, 3 * HID / 32), tb, 0, stream>>>(W1, WT1_hi, 3 * HID, HID);
    transpose_half_kernel<<<dim3((OUT_CH + 31) / 32, HID / 32), tb, 0, stream>>>(Wc, WTc_hi, HID, OUT_CH);

    // degree histograms (LDS-privatized, atomic-free globally)
    hist_kernel<<<dim3(NSLICE, NCHUNK), HTHREADS, 0, stream>>>(row, col, part_row, part_col, E);
    merge_deg_kernel<<<(N + 255) / 256, 256, 0, stream>>>(part_row, part_col, dis, deg_col, N);

    const int NB_SCAN = (N + 255) / 256;   // 196
    scan1_kernel<<<NB_SCAN, 256, 0, stream>>>(deg_col, bsums, N);
    scan2_kernel<<<1, 256, 0, stream>>>(bsums, NB_SCAN);
    scan3_kernel<<<NB_SCAN, 256, 0, stream>>>(deg_col, bsums, offsets, N);
    // chunked fill: LDS cursors + per-(slice,node) offsets from hist prefix
    fill_csr_kernel<<<dim3(NSLICE, NCHUNK), HTHREADS, 0, stream>>>(row, col, dis, offsets,
                                                                   part_col, csr, E);

    // NC=2 grids: 196 panels x 2 col-blocks, swizzle needs grid multiple of 16 -> 400 (guarded)
    const int G2 = 400;
    // h = relu(x @ W_feat + b_feat) -> fp16 hi/lo pair
    mfma_gemm_kernel<1, 1, 2, 0><<<G2, 512, 0, stream>>>(
        x_hi, x_lo, nullptr, nullptr, nullptr, nullptr, WTf_hi, b_feat,
        nullptr, h_hi, h_lo, nullptr, nullptr, N, IN_CH, IN_CH, HID);

    const unsigned short* WThs[2] = {WT0_hi, WT1_hi};
    const float* bs[2]    = {b0, b1};
    const float* gs[2]    = {g0, g1};
    const float* betas[2] = {beta0, beta1};
    int prop_grid = (N + 3) / 4;
    for (int layer = 0; layer < 2; ++layer) {
        prop_kernel<<<prop_grid, 256, 0, stream>>>(h_hi, offsets, csr, agg1_hi, agg1_lo, N);
        prop_kernel<<<prop_grid, 256, 0, stream>>>(agg1_hi, offsets, csr, agg2_hi, agg2_lo, N);
        hipMemsetAsync(sums, 0, HID * 4, stream);
        hipMemsetAsync(sumsq, 0, HID * 4, stream);
        mfma_gemm_kernel<0, 0, 2, 1><<<G2, 512, 0, stream>>>(
            h_hi, h_lo, agg1_hi, agg1_lo, agg2_hi, agg2_lo, WThs[layer], bs[layer],
            y, nullptr, nullptr, sums, sumsq, N, 3 * HID, HID, HID);
        bnrelu_kernel<<<(N * HID / 4 + 255) / 256, 256, 0, stream>>>(y, sums, sumsq, gs[layer],
                                                                     betas[layer], h_hi, h_lo, N);
    }

    mfma_gemm_kernel<0, 0, 1, 0><<<N_PAD / GBM, 512, 0, stream>>>(
        h_hi, h_lo, nullptr, nullptr, nullptr, nullptr, WTc_hi, bc,
        out, nullptr, nullptr, nullptr, nullptr, N, HID, HID, OUT_CH);
}

// Round 15
// 843.173 us; speedup vs baseline: 1.1989x; 1.0305x over previous
//
#include <hip/hip_runtime.h>

#define N_NODES 50000
#define N_PAD   50176            // 196 * 256 = 8 * 6272
#define N_EDGES 1600000
#define IN_CH   512
#define HID     256
#define OUT_CH  40
#define BN_EPS  1e-5f

#define HCHUNK  6272             // hist: nodes per chunk (8 chunks)
#define NCHUNK  8
#define FCHUNK  12544            // fill: nodes per chunk (4 chunks, 49KB LDS)
#define FNCHUNK 4
#define NSLICE  32               // edge slices; E/NSLICE = 50000 exactly
#define HTHREADS 1024

typedef _Float16 f16x8 __attribute__((ext_vector_type(8)));
typedef __attribute__((ext_vector_type(8))) unsigned short u16x8;
typedef __attribute__((ext_vector_type(4))) float f32x4;

__device__ __forceinline__ unsigned short f2h_us(float f) {
    _Float16 h = (_Float16)f;
    return __builtin_bit_cast(unsigned short, h);
}
__device__ __forceinline__ float h2f(unsigned short u) {
    return (float)__builtin_bit_cast(_Float16, u);
}
// split f into fp16 hi + fp16 lo (residual; exact subtraction in fp32)
__device__ __forceinline__ void f2h_split(float f, unsigned short& hi, unsigned short& lo) {
    _Float16 h = (_Float16)f;
    hi = __builtin_bit_cast(unsigned short, h);
    lo = f2h_us(f - (float)h);
}

// async global->LDS, 16B per lane; LDS dest is wave-uniform base + lane*16
__device__ __forceinline__ void gload_lds16(const void* gsrc, void* ldst) {
    __builtin_amdgcn_global_load_lds(
        (const __attribute__((address_space(1))) unsigned int*)gsrc,
        (__attribute__((address_space(3))) unsigned int*)ldst,
        16, 0, 0);
}

// ---------------- degree histograms via LDS privatization (no global atomics) ----------------
__global__ __launch_bounds__(HTHREADS)
void hist_kernel(const int* __restrict__ row, const int* __restrict__ col,
                 int* __restrict__ part_row, int* __restrict__ part_col, int E) {
    __shared__ int hr[HCHUNK];
    __shared__ int hc[HCHUNK];
    int s = blockIdx.x;        // edge slice
    int c = blockIdx.y;        // node chunk
    int base = c * HCHUNK;
    int t = threadIdx.x;
    for (int i = t; i < HCHUNK; i += HTHREADS) { hr[i] = 0; hc[i] = 0; }
    __syncthreads();
    int e0 = s * (E / NSLICE), e1 = e0 + E / NSLICE;
    for (int e = e0 + t; e < e1; e += HTHREADS) {
        int r = row[e], cc = col[e];
        unsigned lr = (unsigned)(r - base);
        unsigned lc = (unsigned)(cc - base);
        if (lr < HCHUNK) atomicAdd(&hr[lr], 1);
        if (lc < HCHUNK) atomicAdd(&hc[lc], 1);
    }
    __syncthreads();
    int* pr = part_row + (size_t)s * N_PAD + base;
    int* pc = part_col + (size_t)s * N_PAD + base;
    for (int i = t; i < HCHUNK; i += HTHREADS) { pr[i] = hr[i]; pc[i] = hc[i]; }
}

// merge + scan1 fused: deg_row -> dis; part_col -> per-node exclusive prefix over slices;
// per-256-node block sum -> bsums
__global__ void merge_scan1_kernel(const int* __restrict__ part_row, int* __restrict__ part_col,
                                   float* __restrict__ dis, int* __restrict__ deg_col,
                                   int* __restrict__ bsums, int n) {
    __shared__ int sd[256];
    int t = threadIdx.x;
    int i = blockIdx.x * 256 + t;
    int run = 0;
    if (i < n) {
        int dr = 0;
        #pragma unroll
        for (int s = 0; s < NSLICE; ++s)
            dr += part_row[(size_t)s * N_PAD + i];
        #pragma unroll
        for (int s = 0; s < NSLICE; ++s) {
            int cnt = part_col[(size_t)s * N_PAD + i];
            part_col[(size_t)s * N_PAD + i] = run;   // exclusive prefix
            run += cnt;
        }
        dis[i] = rsqrtf((float)max(dr, 1));
        deg_col[i] = run;
    }
    sd[t] = (i < n) ? run : 0;
    __syncthreads();
    for (int o = 128; o > 0; o >>= 1) {
        if (t < o) sd[t] += sd[t + o];
        __syncthreads();
    }
    if (t == 0) bsums[blockIdx.x] = sd[0];
}

__global__ void scan2_kernel(int* __restrict__ bsums, int nb) {   // 1 block, 256 threads
    __shared__ int sd[256];
    int t = threadIdx.x;
    int v = (t < nb) ? bsums[t] : 0;
    sd[t] = v;
    __syncthreads();
    for (int o = 1; o < 256; o <<= 1) {
        int u = (t >= o) ? sd[t - o] : 0;
        __syncthreads();
        sd[t] += u;
        __syncthreads();
    }
    if (t < nb) bsums[t] = sd[t] - v;   // exclusive
}

__global__ void scan3_kernel(const int* __restrict__ deg, const int* __restrict__ bsums,
                             int* __restrict__ offsets, int n) {
    __shared__ int sd[256];
    int t = threadIdx.x;
    int i = blockIdx.x * 256 + t;
    sd[t] = (i < n) ? deg[i] : 0;
    __syncthreads();
    for (int o = 1; o < 256; o <<= 1) {
        int u = (t >= o) ? sd[t - o] : 0;
        __syncthreads();
        sd[t] += u;
        __syncthreads();
    }
    if (i < n) offsets[i + 1] = bsums[blockIdx.x] + sd[t];
    if (i == 0) offsets[0] = 0;
}

// ---------------- CSR fill, chunked: LDS cursors + precomputed slice offsets (no global atomics) ----
__global__ __launch_bounds__(HTHREADS)
void fill_csr_kernel(const int* __restrict__ row, const int* __restrict__ col,
                     const float* __restrict__ dis, const int* __restrict__ offsets,
                     const int* __restrict__ part_col, int2* __restrict__ csr, int E) {
    __shared__ int cur[FCHUNK];
    int s = blockIdx.x;        // edge slice
    int c = blockIdx.y;        // node chunk
    int base = c * FCHUNK;
    int t = threadIdx.x;
    for (int i = t; i < FCHUNK; i += HTHREADS) cur[i] = 0;
    __syncthreads();
    int e0 = s * (E / NSLICE), e1 = e0 + E / NSLICE;
    for (int e = e0 + t; e < e1; e += HTHREADS) {
        int r = row[e], cc = col[e];
        unsigned lc = (unsigned)(cc - base);
        if (lc < FCHUNK) {
            int pos = atomicAdd(&cur[lc], 1);
            int idx = offsets[cc] + part_col[(size_t)s * N_PAD + cc] + pos;
            csr[idx] = make_int2(r, __float_as_int(dis[r] * dis[cc]));
        }
    }
}

// ---------------- x hi/lo split (fp16) ----------------
__global__ void split_x_kernel(const float* __restrict__ x, unsigned short* __restrict__ xhi,
                               unsigned short* __restrict__ xlo, int n4) {
    int i = blockIdx.x * blockDim.x + threadIdx.x;
    if (i < n4) {
        float4 v = ((const float4*)x)[i];
        float r[4] = {v.x, v.y, v.z, v.w};
        ushort4 hs, ls;
        unsigned short* hp = (unsigned short*)&hs;
        unsigned short* lp = (unsigned short*)&ls;
        #pragma unroll
        for (int j = 0; j < 4; ++j) f2h_split(r[j], hp[j], lp[j]);
        ((ushort4*)xhi)[i] = hs;
        ((ushort4*)xlo)[i] = ls;
    }
}

// ---------------- propagation (full-row fp16 gather, 8-deep MLP; hi-only output) ----------------
__global__ void prop_kernel(const unsigned short* __restrict__ hsrc,
                            const int* __restrict__ offsets,
                            const int2* __restrict__ csr,
                            unsigned short* __restrict__ Ohi, int n) {
    int node = blockIdx.x * 4 + (threadIdx.x >> 6);
    if (node >= n) return;
    int lane = threadIdx.x & 63;
    int half = lane >> 5;
    int cl   = lane & 31;           // 16B chunk id within the 512B row
    int beg = offsets[node], end = offsets[node + 1];
    float acc[8] = {0.f, 0.f, 0.f, 0.f, 0.f, 0.f, 0.f, 0.f};
    for (int i = beg; i < end; i += 16) {
        float w[8];
        int s[8];
        #pragma unroll
        for (int u = 0; u < 8; ++u) {
            int iu = i + 2 * u + half;
            int2 rec = csr[min(iu, end - 1)];
            w[u] = (iu < end) ? __int_as_float(rec.y) : 0.f;
            s[u] = rec.x;
        }
        u16x8 v[8];
        #pragma unroll
        for (int u = 0; u < 8; ++u)
            v[u] = *(const u16x8*)(hsrc + (size_t)s[u] * HID + cl * 8);
        #pragma unroll
        for (int u = 0; u < 8; ++u)
            #pragma unroll
            for (int j = 0; j < 8; ++j)
                acc[j] += w[u] * h2f((unsigned short)v[u][j]);
    }
    #pragma unroll
    for (int j = 0; j < 8; ++j) acc[j] += __shfl_xor(acc[j], 32);
    if (half == 0) {
        u16x8 ov;
        #pragma unroll
        for (int j = 0; j < 8; ++j) ov[j] = f2h_us(acc[j]);
        *(u16x8*)(Ohi + (size_t)node * HID + cl * 8) = ov;
    }
}

// ---------------- tiled transpose -> single fp16 plane: src[R][C] -> dst[C][R] ----------------
__global__ void transpose_half_kernel(const float* __restrict__ src,
                                      unsigned short* __restrict__ dhi, int R, int C) {
    __shared__ float tile[32][33];
    int c0 = blockIdx.x * 32, r0 = blockIdx.y * 32;
    int tx = threadIdx.x, ty = threadIdx.y;   // block (32, 8)
    #pragma unroll
    for (int i = 0; i < 32; i += 8) {
        int r = r0 + ty + i, c = c0 + tx;
        tile[ty + i][tx] = (r < R && c < C) ? src[(size_t)r * C + c] : 0.f;
    }
    __syncthreads();
    #pragma unroll
    for (int i = 0; i < 32; i += 8) {
        int c = c0 + ty + i, r = r0 + tx;
        if (c < C && r < R) dhi[(size_t)c * R + r] = f2h_us(tile[tx][ty + i]);
    }
}

// ---------------- MFMA GEMM (fp16): 256x128 tile, 8 waves, double-buffered 2-phase ----------------
#define GBM 256
#define GBN 128
#define GBK 32

// ACT: relu; OUTMODE: 0 = fp32 C, 1 = fp16 hi/lo pair; NC: column blocks; STATS: fused BN colstats
// LOMODE: 0 = all segments have lo plane, 1 = only segment 0 (k0 < seg) has lo
template<int ACT, int OUTMODE, int NC, int STATS, int LOMODE>
__global__ __launch_bounds__(512)
void mfma_gemm_kernel(const unsigned short* __restrict__ A0h, const unsigned short* __restrict__ A0l,
                      const unsigned short* __restrict__ A1h,
                      const unsigned short* __restrict__ A2h,
                      const unsigned short* __restrict__ Wh,
                      const float* __restrict__ bvec,
                      float* __restrict__ C, unsigned short* __restrict__ Chi,
                      unsigned short* __restrict__ Clo,
                      float* __restrict__ bn_sums, float* __restrict__ bn_sumsq,
                      int M, int K, int seg, int Kout) {
    // [buf][kgroup(4)][row][8 f16]: A planes 16KB/buf, B plane 8KB/buf -> 80KB total (2 blocks/CU)
    __shared__ __attribute__((aligned(16))) unsigned short As_hi[2][4 * GBM * 8];
    __shared__ __attribute__((aligned(16))) unsigned short As_lo[2][4 * GBM * 8];
    __shared__ __attribute__((aligned(16))) unsigned short Bs_hi[2][4 * GBN * 8];

    int tid  = threadIdx.x;
    int lane = tid & 63;
    int w    = tid >> 6;                   // wave id 0..7
    int wm   = w & 3, wn = w >> 2;         // 4x2 waves, 64x64 output each
    int kg   = lane >> 4, lr = lane & 15;  // fragment lane decomposition
    int kgq  = w & 3, hf = w >> 2;         // staging role: kgroup + half

    int bid = blockIdx.x, p, c;
    if (NC == 2) {
        p = ((bid >> 4) << 3) + (bid & 7);
        c = (bid >> 3) & 1;
        if (p >= N_PAD / GBM) return;      // grid padded to multiple of 16
    } else { p = bid; c = 0; }
    int bm = p * GBM, bn = c * GBN;

    f32x4 acc[4][4];
    #pragma unroll
    for (int i = 0; i < 4; ++i)
        #pragma unroll
        for (int j = 0; j < 4; ++j)
            acc[i][j] = (f32x4){0.f, 0.f, 0.f, 0.f};

    // stage: 2 A_hi + (2 A_lo if segment has lo) + 1 B per wave
    auto STAGE = [&](int buf, int k0) {
        const unsigned short *Aph, *Apl; int kl0;
        if (k0 < seg)          { Aph = A0h; Apl = A0l; kl0 = k0; }
        else if (k0 < 2 * seg) { Aph = A1h; Apl = nullptr; kl0 = k0 - seg; }
        else                   { Aph = A2h; Apl = nullptr; kl0 = k0 - 2 * seg; }
        size_t rA = (size_t)64 * seg;
        const unsigned short* a_h = Aph + (size_t)(bm + hf * 128 + lane) * seg + kl0 + kgq * 8;
        gload_lds16(a_h,      &As_hi[buf][(kgq * GBM + hf * 128)      * 8]);
        gload_lds16(a_h + rA, &As_hi[buf][(kgq * GBM + hf * 128 + 64) * 8]);
        if (LOMODE == 0 || k0 < seg) {
            const unsigned short* a_l = Apl + (size_t)(bm + hf * 128 + lane) * seg + kl0 + kgq * 8;
            gload_lds16(a_l,      &As_lo[buf][(kgq * GBM + hf * 128)      * 8]);
            gload_lds16(a_l + rA, &As_lo[buf][(kgq * GBM + hf * 128 + 64) * 8]);
        }
        const unsigned short* b_h = Wh + (size_t)(bn + hf * 64 + lane) * K + k0 + kgq * 8;
        gload_lds16(b_h,      &Bs_hi[buf][(kgq * GBN + hf * 64)       * 8]);
    };

    int nt = K / GBK;
    STAGE(0, 0);
    asm volatile("s_waitcnt vmcnt(0)" ::: "memory");
    __builtin_amdgcn_s_barrier();
    __builtin_amdgcn_sched_barrier(0);

    for (int t = 0; t < nt; ++t) {
        int cur = t & 1;
        if (t + 1 < nt) STAGE(cur ^ 1, (t + 1) * GBK);   // overlaps this step's compute

        int abase = (kg * GBM + wm * 64 + lr) * 8;
        int bbase = (kg * GBN + wn * 64 + lr) * 8;
        f16x8 ah[4], bh[4];
        #pragma unroll
        for (int mf = 0; mf < 4; ++mf)
            ah[mf] = *(const f16x8*)&As_hi[cur][abase + mf * 16 * 8];
        #pragma unroll
        for (int nf = 0; nf < 4; ++nf)
            bh[nf] = *(const f16x8*)&Bs_hi[cur][bbase + nf * 16 * 8];
        #pragma unroll
        for (int mf = 0; mf < 4; ++mf)
            #pragma unroll
            for (int nf = 0; nf < 4; ++nf)
                acc[mf][nf] = __builtin_amdgcn_mfma_f32_16x16x32_f16(ah[mf], bh[nf], acc[mf][nf], 0, 0, 0);
        if (LOMODE == 0 || t * GBK < seg) {
            f16x8 al[4];
            #pragma unroll
            for (int mf = 0; mf < 4; ++mf)
                al[mf] = *(const f16x8*)&As_lo[cur][abase + mf * 16 * 8];
            #pragma unroll
            for (int mf = 0; mf < 4; ++mf)
                #pragma unroll
                for (int nf = 0; nf < 4; ++nf)
                    acc[mf][nf] = __builtin_amdgcn_mfma_f32_16x16x32_f16(al[mf], bh[nf], acc[mf][nf], 0, 0, 0);
        }

        asm volatile("s_waitcnt vmcnt(0)" ::: "memory");  // next tile landed
        __builtin_amdgcn_s_barrier();                     // all waves done reading buf cur
        __builtin_amdgcn_sched_barrier(0);
    }

    // ---- epilogue: C/D layout col = lane&15, row = (lane>>4)*4 + reg ----
    #pragma unroll
    for (int nf = 0; nf < 4; ++nf) {
        int col = bn + wn * 64 + nf * 16 + lr;
        if (col >= Kout) continue;
        float bv = bvec[col];
        float s1 = 0.f, s2 = 0.f;
        #pragma unroll
        for (int mf = 0; mf < 4; ++mf) {
            #pragma unroll
            for (int i = 0; i < 4; ++i) {
                int rw = bm + wm * 64 + mf * 16 + kg * 4 + i;
                if (rw < M) {
                    float v = acc[mf][nf][i] + bv;
                    if (ACT == 1) v = fmaxf(v, 0.f);
                    if (STATS) { s1 += v; s2 += v * v; }
                    if (OUTMODE == 0) {
                        C[(size_t)rw * Kout + col] = v;
                    } else {
                        unsigned short hs, ls;
                        f2h_split(v, hs, ls);
                        Chi[(size_t)rw * Kout + col] = hs;
                        Clo[(size_t)rw * Kout + col] = ls;
                    }
                }
            }
        }
        if (STATS) {
            s1 += __shfl_xor(s1, 16); s1 += __shfl_xor(s1, 32);
            s2 += __shfl_xor(s2, 16); s2 += __shfl_xor(s2, 32);
            if (kg == 0) {
                atomicAdd(&bn_sums[col], s1);
                atomicAdd(&bn_sumsq[col], s2);
            }
        }
    }
}

__global__ void bnrelu_kernel(const float* __restrict__ y, const float* __restrict__ sums,
                              const float* __restrict__ sumsq, const float* __restrict__ g,
                              const float* __restrict__ beta,
                              unsigned short* __restrict__ Hhi, unsigned short* __restrict__ Hlo,
                              int M) {
    int idx = blockIdx.x * blockDim.x + threadIdx.x;   // group of 4 channels
    if (idx < M * HID / 4) {
        int col0 = (idx * 4) & (HID - 1);
        float4 v = ((const float4*)y)[idx];
        float invM = 1.0f / (float)M;
        float r[4] = {v.x, v.y, v.z, v.w};
        ushort4 hs, ls;
        unsigned short* hp = (unsigned short*)&hs;
        unsigned short* lp = (unsigned short*)&ls;
        #pragma unroll
        for (int j = 0; j < 4; ++j) {
            int col = col0 + j;
            float mean = sums[col] * invM;
            float var  = fmaxf(sumsq[col] * invM - mean * mean, 0.f);
            float o = (r[j] - mean) * rsqrtf(var + BN_EPS) * g[col] + beta[col];
            o = fmaxf(o, 0.f);
            f2h_split(o, hp[j], lp[j]);
        }
        ((ushort4*)Hhi)[idx] = hs;
        ((ushort4*)Hlo)[idx] = ls;
    }
}

extern "C" void kernel_launch(void* const* d_in, const int* in_sizes, int n_in,
                              void* d_out, int out_size, void* d_ws, size_t ws_size,
                              hipStream_t stream) {
    const float* x      = (const float*)d_in[0];
    const int*   ei     = (const int*)d_in[1];
    const float* W_feat = (const float*)d_in[2];
    const float* b_feat = (const float*)d_in[3];
    const float* W0     = (const float*)d_in[4];
    const float* b0     = (const float*)d_in[5];
    const float* g0     = (const float*)d_in[6];
    const float* beta0  = (const float*)d_in[7];
    const float* W1     = (const float*)d_in[8];
    const float* b1     = (const float*)d_in[9];
    const float* g1     = (const float*)d_in[10];
    const float* beta1  = (const float*)d_in[11];
    const float* Wc     = (const float*)d_in[12];
    const float* bc     = (const float*)d_in[13];
    float* out = (float*)d_out;

    const int N = N_NODES, E = N_EDGES;
    const int* row = ei;
    const int* col = ei + E;

    // workspace carve-up
    char* ws = (char*)d_ws;
    size_t off = 0;
    auto alloc = [&](size_t bytes) -> void* {
        void* p = ws + off;
        off = (off + bytes + 255) & ~(size_t)255;
        return p;
    };
    int*   deg_col  = (int*)  alloc(N * 4);
    int*   offsets  = (int*)  alloc((N + 1) * 4);
    int*   bsums    = (int*)  alloc(256 * 4);
    float* dis      = (float*)alloc(N * 4);
    int*   part_row = (int*)  alloc((size_t)NSLICE * N_PAD * 4);
    int*   part_col = (int*)  alloc((size_t)NSLICE * N_PAD * 4);
    int2*  csr      = (int2*) alloc((size_t)E * 8);
    unsigned short* x_hi    = (unsigned short*)alloc((size_t)N_PAD * IN_CH * 2);
    unsigned short* x_lo    = (unsigned short*)alloc((size_t)N_PAD * IN_CH * 2);
    unsigned short* h_hi    = (unsigned short*)alloc((size_t)N_PAD * HID * 2);
    unsigned short* h_lo    = (unsigned short*)alloc((size_t)N_PAD * HID * 2);
    unsigned short* agg1_hi = (unsigned short*)alloc((size_t)N_PAD * HID * 2);
    // lifetime aliasing: x_hi/x_lo are dead after the feat GEMM; reuse the region
    unsigned short* agg2_hi = x_hi;
    float*          y       = (float*)x_lo;
    float* sums     = (float*)alloc(HID * 4);
    float* sumsq    = (float*)alloc(HID * 4);
    unsigned short* WTf_hi = (unsigned short*)alloc((size_t)HID * IN_CH * 2);
    unsigned short* WT0_hi = (unsigned short*)alloc((size_t)HID * 3 * HID * 2);
    unsigned short* WT1_hi = (unsigned short*)alloc((size_t)HID * 3 * HID * 2);
    unsigned short* WTc_hi = (unsigned short*)alloc((size_t)128 * HID * 2);   // 40 rows padded to 128

    hipMemsetAsync(WTc_hi, 0, (size_t)128 * HID * 2, stream);

    // operand pre-splits (independent of CSR build)
    split_x_kernel<<<(N * IN_CH / 4 + 255) / 256, 256, 0, stream>>>(x, x_hi, x_lo, N * IN_CH / 4);
    dim3 tb(32, 8);
    transpose_half_kernel<<<dim3(HID / 32, IN_CH / 32), tb, 0, stream>>>(W_feat, WTf_hi, IN_CH, HID);
    transpose_half_kernel<<<dim3(HID / 32, 3 * HID / 32), tb, 0, stream>>>(W0, WT0_hi, 3 * HID, HID);
    transpose_half_kernel<<<dim3(HID / 32, 3 * HID / 32), tb, 0, stream>>>(W1, WT1_hi, 3 * HID, HID);
    transpose_half_kernel<<<dim3((OUT_CH + 31) / 32, HID / 32), tb, 0, stream>>>(Wc, WTc_hi, HID, OUT_CH);

    // degree histograms (LDS-privatized, atomic-free globally)
    hist_kernel<<<dim3(NSLICE, NCHUNK), HTHREADS, 0, stream>>>(row, col, part_row, part_col, E);

    const int NB_SCAN = (N + 255) / 256;   // 196
    merge_scan1_kernel<<<NB_SCAN, 256, 0, stream>>>(part_row, part_col, dis, deg_col, bsums, N);
    scan2_kernel<<<1, 256, 0, stream>>>(bsums, NB_SCAN);
    scan3_kernel<<<NB_SCAN, 256, 0, stream>>>(deg_col, bsums, offsets, N);
    // chunked fill: LDS cursors + per-(slice,node) offsets from hist prefix
    fill_csr_kernel<<<dim3(NSLICE, FNCHUNK), HTHREADS, 0, stream>>>(row, col, dis, offsets,
                                                                    part_col, csr, E);

    // NC=2 grids: 196 panels x 2 col-blocks, swizzle needs grid multiple of 16 -> 400 (guarded)
    const int G2 = 400;
    // h = relu(x @ W_feat + b_feat) -> fp16 hi/lo pair
    mfma_gemm_kernel<1, 1, 2, 0, 0><<<G2, 512, 0, stream>>>(
        x_hi, x_lo, nullptr, nullptr, WTf_hi, b_feat,
        nullptr, h_hi, h_lo, nullptr, nullptr, N, IN_CH, IN_CH, HID);

    const unsigned short* WThs[2] = {WT0_hi, WT1_hi};
    const float* bs[2]    = {b0, b1};
    const float* gs[2]    = {g0, g1};
    const float* betas[2] = {beta0, beta1};
    int prop_grid = (N + 3) / 4;
    for (int layer = 0; layer < 2; ++layer) {
        prop_kernel<<<prop_grid, 256, 0, stream>>>(h_hi, offsets, csr, agg1_hi, N);
        prop_kernel<<<prop_grid, 256, 0, stream>>>(agg1_hi, offsets, csr, agg2_hi, N);
        hipMemsetAsync(sums, 0, HID * 4, stream);
        hipMemsetAsync(sumsq, 0, HID * 4, stream);
        mfma_gemm_kernel<0, 0, 2, 1, 1><<<G2, 512, 0, stream>>>(
            h_hi, h_lo, agg1_hi, agg2_hi, WThs[layer], bs[layer],
            y, nullptr, nullptr, sums, sumsq, N, 3 * HID, HID, HID);
        bnrelu_kernel<<<(N * HID / 4 + 255) / 256, 256, 0, stream>>>(y, sums, sumsq, gs[layer],
                                                                     betas[layer], h_hi, h_lo, N);
    }

    mfma_gemm_kernel<0, 0, 1, 0, 0><<<N_PAD / GBM, 512, 0, stream>>>(
        h_hi, h_lo, nullptr, nullptr, WTc_hi, bc,
        out, nullptr, nullptr, nullptr, nullptr, N, HID, HID, OUT_CH);
}

// Round 16
// 828.533 us; speedup vs baseline: 1.2201x; 1.0177x over previous
//
#include <hip/hip_runtime.h>

#define N_NODES 50000
#define N_PAD   50176            // 196 * 256
#define N_EDGES 1600000
#define IN_CH   512
#define HID     256
#define OUT_CH  40
#define BN_EPS  1e-5f

#define HCHUNK  12544            // hist: nodes per chunk (4 chunks, 100KB LDS)
#define NCHUNK  4
#define FCHUNK  25088            // fill: nodes per chunk (2 chunks, 100KB LDS)
#define FNCHUNK 2
#define NSLICE  32               // edge slices; E/NSLICE = 50000 exactly
#define HTHREADS 1024

typedef _Float16 f16x8 __attribute__((ext_vector_type(8)));
typedef __attribute__((ext_vector_type(8))) unsigned short u16x8;
typedef __attribute__((ext_vector_type(4))) float f32x4;

__device__ __forceinline__ unsigned short f2h_us(float f) {
    _Float16 h = (_Float16)f;
    return __builtin_bit_cast(unsigned short, h);
}
__device__ __forceinline__ float h2f(unsigned short u) {
    return (float)__builtin_bit_cast(_Float16, u);
}

// async global->LDS, 16B per lane; LDS dest is wave-uniform base + lane*16
__device__ __forceinline__ void gload_lds16(const void* gsrc, void* ldst) {
    __builtin_amdgcn_global_load_lds(
        (const __attribute__((address_space(1))) unsigned int*)gsrc,
        (__attribute__((address_space(3))) unsigned int*)ldst,
        16, 0, 0);
}

// ---------------- degree histograms via LDS privatization (no global atomics) ----------------
__global__ __launch_bounds__(HTHREADS)
void hist_kernel(const int* __restrict__ row, const int* __restrict__ col,
                 int* __restrict__ part_row, int* __restrict__ part_col, int E) {
    __shared__ int hr[HCHUNK];
    __shared__ int hc[HCHUNK];
    int s = blockIdx.x;        // edge slice
    int c = blockIdx.y;        // node chunk
    int base = c * HCHUNK;
    int t = threadIdx.x;
    for (int i = t; i < HCHUNK; i += HTHREADS) { hr[i] = 0; hc[i] = 0; }
    __syncthreads();
    int e0 = s * (E / NSLICE), e1 = e0 + E / NSLICE;
    for (int e = e0 + t; e < e1; e += HTHREADS) {
        int r = row[e], cc = col[e];
        unsigned lr = (unsigned)(r - base);
        unsigned lc = (unsigned)(cc - base);
        if (lr < HCHUNK) atomicAdd(&hr[lr], 1);
        if (lc < HCHUNK) atomicAdd(&hc[lc], 1);
    }
    __syncthreads();
    int* pr = part_row + (size_t)s * N_PAD + base;
    int* pc = part_col + (size_t)s * N_PAD + base;
    for (int i = t; i < HCHUNK; i += HTHREADS) { pr[i] = hr[i]; pc[i] = hc[i]; }
}

// merge + scan1 fused: deg_row -> dis; part_col -> per-node exclusive prefix over slices;
// per-256-node block sum -> bsums
__global__ void merge_scan1_kernel(const int* __restrict__ part_row, int* __restrict__ part_col,
                                   float* __restrict__ dis, int* __restrict__ deg_col,
                                   int* __restrict__ bsums, int n) {
    __shared__ int sd[256];
    int t = threadIdx.x;
    int i = blockIdx.x * 256 + t;
    int run = 0;
    if (i < n) {
        int dr = 0;
        #pragma unroll
        for (int s = 0; s < NSLICE; ++s)
            dr += part_row[(size_t)s * N_PAD + i];
        #pragma unroll
        for (int s = 0; s < NSLICE; ++s) {
            int cnt = part_col[(size_t)s * N_PAD + i];
            part_col[(size_t)s * N_PAD + i] = run;   // exclusive prefix
            run += cnt;
        }
        dis[i] = rsqrtf((float)max(dr, 1));
        deg_col[i] = run;
    }
    sd[t] = (i < n) ? run : 0;
    __syncthreads();
    for (int o = 128; o > 0; o >>= 1) {
        if (t < o) sd[t] += sd[t + o];
        __syncthreads();
    }
    if (t == 0) bsums[blockIdx.x] = sd[0];
}

__global__ void scan2_kernel(int* __restrict__ bsums, int nb) {   // 1 block, 256 threads
    __shared__ int sd[256];
    int t = threadIdx.x;
    int v = (t < nb) ? bsums[t] : 0;
    sd[t] = v;
    __syncthreads();
    for (int o = 1; o < 256; o <<= 1) {
        int u = (t >= o) ? sd[t - o] : 0;
        __syncthreads();
        sd[t] += u;
        __syncthreads();
    }
    if (t < nb) bsums[t] = sd[t] - v;   // exclusive
}

__global__ void scan3_kernel(const int* __restrict__ deg, const int* __restrict__ bsums,
                             int* __restrict__ offsets, int n) {
    __shared__ int sd[256];
    int t = threadIdx.x;
    int i = blockIdx.x * 256 + t;
    sd[t] = (i < n) ? deg[i] : 0;
    __syncthreads();
    for (int o = 1; o < 256; o <<= 1) {
        int u = (t >= o) ? sd[t - o] : 0;
        __syncthreads();
        sd[t] += u;
        __syncthreads();
    }
    if (i < n) offsets[i + 1] = bsums[blockIdx.x] + sd[t];
    if (i == 0) offsets[0] = 0;
}

// ---------------- CSR fill, chunked: LDS cursors + precomputed slice offsets (no global atomics) ----
__global__ __launch_bounds__(HTHREADS)
void fill_csr_kernel(const int* __restrict__ row, const int* __restrict__ col,
                     const float* __restrict__ dis, const int* __restrict__ offsets,
                     const int* __restrict__ part_col, int2* __restrict__ csr, int E) {
    __shared__ int cur[FCHUNK];
    int s = blockIdx.x;        // edge slice
    int c = blockIdx.y;        // node chunk
    int base = c * FCHUNK;
    int t = threadIdx.x;
    for (int i = t; i < FCHUNK; i += HTHREADS) cur[i] = 0;
    __syncthreads();
    int e0 = s * (E / NSLICE), e1 = e0 + E / NSLICE;
    for (int e = e0 + t; e < e1; e += HTHREADS) {
        int r = row[e], cc = col[e];
        unsigned lc = (unsigned)(cc - base);
        if (lc < FCHUNK) {
            int pos = atomicAdd(&cur[lc], 1);
            int idx = offsets[cc] + part_col[(size_t)s * N_PAD + cc] + pos;
            csr[idx] = make_int2(r, __float_as_int(dis[r] * dis[cc]));
        }
    }
}

// ---------------- x -> fp16 convert ----------------
__global__ void convert_x_kernel(const float* __restrict__ x, unsigned short* __restrict__ xhi,
                                 int n4) {
    int i = blockIdx.x * blockDim.x + threadIdx.x;
    if (i < n4) {
        float4 v = ((const float4*)x)[i];
        float r[4] = {v.x, v.y, v.z, v.w};
        ushort4 hs;
        unsigned short* hp = (unsigned short*)&hs;
        #pragma unroll
        for (int j = 0; j < 4; ++j) hp[j] = f2h_us(r[j]);
        ((ushort4*)xhi)[i] = hs;
    }
}

// ---------------- propagation (full-row fp16 gather, 8-deep MLP; hi-only output) ----------------
__global__ void prop_kernel(const unsigned short* __restrict__ hsrc,
                            const int* __restrict__ offsets,
                            const int2* __restrict__ csr,
                            unsigned short* __restrict__ Ohi, int n) {
    int node = blockIdx.x * 4 + (threadIdx.x >> 6);
    if (node >= n) return;
    int lane = threadIdx.x & 63;
    int half = lane >> 5;
    int cl   = lane & 31;           // 16B chunk id within the 512B row
    int beg = offsets[node], end = offsets[node + 1];
    float acc[8] = {0.f, 0.f, 0.f, 0.f, 0.f, 0.f, 0.f, 0.f};
    for (int i = beg; i < end; i += 16) {
        float w[8];
        int s[8];
        #pragma unroll
        for (int u = 0; u < 8; ++u) {
            int iu = i + 2 * u + half;
            int2 rec = csr[min(iu, end - 1)];
            w[u] = (iu < end) ? __int_as_float(rec.y) : 0.f;
            s[u] = rec.x;
        }
        u16x8 v[8];
        #pragma unroll
        for (int u = 0; u < 8; ++u)
            v[u] = *(const u16x8*)(hsrc + (size_t)s[u] * HID + cl * 8);
        #pragma unroll
        for (int u = 0; u < 8; ++u)
            #pragma unroll
            for (int j = 0; j < 8; ++j)
                acc[j] += w[u] * h2f((unsigned short)v[u][j]);
    }
    #pragma unroll
    for (int j = 0; j < 8; ++j) acc[j] += __shfl_xor(acc[j], 32);
    if (half == 0) {
        u16x8 ov;
        #pragma unroll
        for (int j = 0; j < 8; ++j) ov[j] = f2h_us(acc[j]);
        *(u16x8*)(Ohi + (size_t)node * HID + cl * 8) = ov;
    }
}

// ---------------- tiled transpose -> single fp16 plane: src[R][C] -> dst[C][R] ----------------
__global__ void transpose_half_kernel(const float* __restrict__ src,
                                      unsigned short* __restrict__ dhi, int R, int C) {
    __shared__ float tile[32][33];
    int c0 = blockIdx.x * 32, r0 = blockIdx.y * 32;
    int tx = threadIdx.x, ty = threadIdx.y;   // block (32, 8)
    #pragma unroll
    for (int i = 0; i < 32; i += 8) {
        int r = r0 + ty + i, c = c0 + tx;
        tile[ty + i][tx] = (r < R && c < C) ? src[(size_t)r * C + c] : 0.f;
    }
    __syncthreads();
    #pragma unroll
    for (int i = 0; i < 32; i += 8) {
        int c = c0 + ty + i, r = r0 + tx;
        if (c < C && r < R) dhi[(size_t)c * R + r] = f2h_us(tile[tx][ty + i]);
    }
}

// ---------------- MFMA GEMM (fp16, single-plane A): 256x128 tile, 8 waves, 2-phase dbuf ------
#define GBM 256
#define GBN 128
#define GBK 32

// ACT: relu; OUTMODE: 0 = fp32 C, 1 = fp16 C; NC: column blocks; STATS: fused BN colstats
template<int ACT, int OUTMODE, int NC, int STATS>
__global__ __launch_bounds__(512)
void mfma_gemm_kernel(const unsigned short* __restrict__ A0h,
                      const unsigned short* __restrict__ A1h,
                      const unsigned short* __restrict__ A2h,
                      const unsigned short* __restrict__ Wh,
                      const float* __restrict__ bvec,
                      float* __restrict__ C, unsigned short* __restrict__ Chi,
                      float* __restrict__ bn_sums, float* __restrict__ bn_sumsq,
                      int M, int K, int seg, int Kout) {
    // [buf][kgroup(4)][row][8 f16]: A 16KB/buf, B 8KB/buf -> 48KB total (3 blocks/CU)
    __shared__ __attribute__((aligned(16))) unsigned short As_hi[2][4 * GBM * 8];
    __shared__ __attribute__((aligned(16))) unsigned short Bs_hi[2][4 * GBN * 8];

    int tid  = threadIdx.x;
    int lane = tid & 63;
    int w    = tid >> 6;                   // wave id 0..7
    int wm   = w & 3, wn = w >> 2;         // 4x2 waves, 64x64 output each
    int kg   = lane >> 4, lr = lane & 15;  // fragment lane decomposition
    int kgq  = w & 3, hf = w >> 2;         // staging role: kgroup + half

    int bid = blockIdx.x, p, c;
    if (NC == 2) {
        p = ((bid >> 4) << 3) + (bid & 7);
        c = (bid >> 3) & 1;
        if (p >= N_PAD / GBM) return;      // grid padded to multiple of 16
    } else { p = bid; c = 0; }
    int bm = p * GBM, bn = c * GBN;

    f32x4 acc[4][4];
    #pragma unroll
    for (int i = 0; i < 4; ++i)
        #pragma unroll
        for (int j = 0; j < 4; ++j)
            acc[i][j] = (f32x4){0.f, 0.f, 0.f, 0.f};

    // stage: 2 A + 1 B gload_lds per wave
    auto STAGE = [&](int buf, int k0) {
        const unsigned short *Aph; int kl0;
        if (k0 < seg)          { Aph = A0h; kl0 = k0; }
        else if (k0 < 2 * seg) { Aph = A1h; kl0 = k0 - seg; }
        else                   { Aph = A2h; kl0 = k0 - 2 * seg; }
        size_t rA = (size_t)64 * seg;
        const unsigned short* a_h = Aph + (size_t)(bm + hf * 128 + lane) * seg + kl0 + kgq * 8;
        gload_lds16(a_h,      &As_hi[buf][(kgq * GBM + hf * 128)      * 8]);
        gload_lds16(a_h + rA, &As_hi[buf][(kgq * GBM + hf * 128 + 64) * 8]);
        const unsigned short* b_h = Wh + (size_t)(bn + hf * 64 + lane) * K + k0 + kgq * 8;
        gload_lds16(b_h,      &Bs_hi[buf][(kgq * GBN + hf * 64)       * 8]);
    };

    int nt = K / GBK;
    STAGE(0, 0);
    asm volatile("s_waitcnt vmcnt(0)" ::: "memory");
    __builtin_amdgcn_s_barrier();
    __builtin_amdgcn_sched_barrier(0);

    for (int t = 0; t < nt; ++t) {
        int cur = t & 1;
        if (t + 1 < nt) STAGE(cur ^ 1, (t + 1) * GBK);   // overlaps this step's compute

        int abase = (kg * GBM + wm * 64 + lr) * 8;
        int bbase = (kg * GBN + wn * 64 + lr) * 8;
        f16x8 ah[4], bh[4];
        #pragma unroll
        for (int mf = 0; mf < 4; ++mf)
            ah[mf] = *(const f16x8*)&As_hi[cur][abase + mf * 16 * 8];
        #pragma unroll
        for (int nf = 0; nf < 4; ++nf)
            bh[nf] = *(const f16x8*)&Bs_hi[cur][bbase + nf * 16 * 8];
        #pragma unroll
        for (int mf = 0; mf < 4; ++mf)
            #pragma unroll
            for (int nf = 0; nf < 4; ++nf)
                acc[mf][nf] = __builtin_amdgcn_mfma_f32_16x16x32_f16(ah[mf], bh[nf], acc[mf][nf], 0, 0, 0);

        asm volatile("s_waitcnt vmcnt(0)" ::: "memory");  // next tile landed
        __builtin_amdgcn_s_barrier();                     // all waves done reading buf cur
        __builtin_amdgcn_sched_barrier(0);
    }

    // ---- epilogue: C/D layout col = lane&15, row = (lane>>4)*4 + reg ----
    #pragma unroll
    for (int nf = 0; nf < 4; ++nf) {
        int col = bn + wn * 64 + nf * 16 + lr;
        if (col >= Kout) continue;
        float bv = bvec[col];
        float s1 = 0.f, s2 = 0.f;
        #pragma unroll
        for (int mf = 0; mf < 4; ++mf) {
            #pragma unroll
            for (int i = 0; i < 4; ++i) {
                int rw = bm + wm * 64 + mf * 16 + kg * 4 + i;
                if (rw < M) {
                    float v = acc[mf][nf][i] + bv;
                    if (ACT == 1) v = fmaxf(v, 0.f);
                    if (STATS) { s1 += v; s2 += v * v; }
                    if (OUTMODE == 0) {
                        C[(size_t)rw * Kout + col] = v;
                    } else {
                        Chi[(size_t)rw * Kout + col] = f2h_us(v);
                    }
                }
            }
        }
        if (STATS) {
            s1 += __shfl_xor(s1, 16); s1 += __shfl_xor(s1, 32);
            s2 += __shfl_xor(s2, 16); s2 += __shfl_xor(s2, 32);
            if (kg == 0) {
                atomicAdd(&bn_sums[col], s1);
                atomicAdd(&bn_sumsq[col], s2);
            }
        }
    }
}

__global__ void bnrelu_kernel(const float* __restrict__ y, const float* __restrict__ sums,
                              const float* __restrict__ sumsq, const float* __restrict__ g,
                              const float* __restrict__ beta,
                              unsigned short* __restrict__ Hhi, int M) {
    int idx = blockIdx.x * blockDim.x + threadIdx.x;   // group of 4 channels
    if (idx < M * HID / 4) {
        int col0 = (idx * 4) & (HID - 1);
        float4 v = ((const float4*)y)[idx];
        float invM = 1.0f / (float)M;
        float r[4] = {v.x, v.y, v.z, v.w};
        ushort4 hs;
        unsigned short* hp = (unsigned short*)&hs;
        #pragma unroll
        for (int j = 0; j < 4; ++j) {
            int col = col0 + j;
            float mean = sums[col] * invM;
            float var  = fmaxf(sumsq[col] * invM - mean * mean, 0.f);
            float o = (r[j] - mean) * rsqrtf(var + BN_EPS) * g[col] + beta[col];
            o = fmaxf(o, 0.f);
            hp[j] = f2h_us(o);
        }
        ((ushort4*)Hhi)[idx] = hs;
    }
}

extern "C" void kernel_launch(void* const* d_in, const int* in_sizes, int n_in,
                              void* d_out, int out_size, void* d_ws, size_t ws_size,
                              hipStream_t stream) {
    const float* x      = (const float*)d_in[0];
    const int*   ei     = (const int*)d_in[1];
    const float* W_feat = (const float*)d_in[2];
    const float* b_feat = (const float*)d_in[3];
    const float* W0     = (const float*)d_in[4];
    const float* b0     = (const float*)d_in[5];
    const float* g0     = (const float*)d_in[6];
    const float* beta0  = (const float*)d_in[7];
    const float* W1     = (const float*)d_in[8];
    const float* b1     = (const float*)d_in[9];
    const float* g1     = (const float*)d_in[10];
    const float* beta1  = (const float*)d_in[11];
    const float* Wc     = (const float*)d_in[12];
    const float* bc     = (const float*)d_in[13];
    float* out = (float*)d_out;

    const int N = N_NODES, E = N_EDGES;
    const int* row = ei;
    const int* col = ei + E;

    // workspace carve-up
    char* ws = (char*)d_ws;
    size_t off = 0;
    auto alloc = [&](size_t bytes) -> void* {
        void* p = ws + off;
        off = (off + bytes + 255) & ~(size_t)255;
        return p;
    };
    int*   deg_col  = (int*)  alloc(N * 4);
    int*   offsets  = (int*)  alloc((N + 1) * 4);
    int*   bsums    = (int*)  alloc(256 * 4);
    float* dis      = (float*)alloc(N * 4);
    int*   part_row = (int*)  alloc((size_t)NSLICE * N_PAD * 4);
    int*   part_col = (int*)  alloc((size_t)NSLICE * N_PAD * 4);
    int2*  csr      = (int2*) alloc((size_t)E * 8);
    unsigned short* x_hi    = (unsigned short*)alloc((size_t)N_PAD * IN_CH * 2);
    unsigned short* h_hi    = (unsigned short*)alloc((size_t)N_PAD * HID * 2);
    unsigned short* agg1_hi = (unsigned short*)alloc((size_t)N_PAD * HID * 2);
    float*          y       = (float*)alloc((size_t)N_PAD * HID * 4);
    // lifetime aliasing: x_hi is dead after the feat GEMM; reuse the region
    unsigned short* agg2_hi = x_hi;
    float* sums     = (float*)alloc(HID * 4);
    float* sumsq    = (float*)alloc(HID * 4);
    unsigned short* WTf_hi = (unsigned short*)alloc((size_t)HID * IN_CH * 2);
    unsigned short* WT0_hi = (unsigned short*)alloc((size_t)HID * 3 * HID * 2);
    unsigned short* WT1_hi = (unsigned short*)alloc((size_t)HID * 3 * HID * 2);
    unsigned short* WTc_hi = (unsigned short*)alloc((size_t)128 * HID * 2);   // 40 rows padded to 128

    hipMemsetAsync(WTc_hi, 0, (size_t)128 * HID * 2, stream);

    // operand pre-converts (independent of CSR build)
    convert_x_kernel<<<(N * IN_CH / 4 + 255) / 256, 256, 0, stream>>>(x, x_hi, N * IN_CH / 4);
    dim3 tb(32, 8);
    transpose_half_kernel<<<dim3(HID / 32, IN_CH / 32), tb, 0, stream>>>(W_feat, WTf_hi, IN_CH, HID);
    transpose_half_kernel<<<dim3(HID / 32, 3 * HID / 32), tb, 0, stream>>>(W0, WT0_hi, 3 * HID, HID);
    transpose_half_kernel<<<dim3(HID / 32, 3 * HID / 32), tb, 0, stream>>>(W1, WT1_hi, 3 * HID, HID);
    transpose_half_kernel<<<dim3((OUT_CH + 31) / 32, HID / 32), tb, 0, stream>>>(Wc, WTc_hi, HID, OUT_CH);

    // degree histograms (LDS-privatized, atomic-free globally)
    hist_kernel<<<dim3(NSLICE, NCHUNK), HTHREADS, 0, stream>>>(row, col, part_row, part_col, E);

    const int NB_SCAN = (N + 255) / 256;   // 196
    merge_scan1_kernel<<<NB_SCAN, 256, 0, stream>>>(part_row, part_col, dis, deg_col, bsums, N);
    scan2_kernel<<<1, 256, 0, stream>>>(bsums, NB_SCAN);
    scan3_kernel<<<NB_SCAN, 256, 0, stream>>>(deg_col, bsums, offsets, N);
    // chunked fill: LDS cursors + per-(slice,node) offsets from hist prefix
    fill_csr_kernel<<<dim3(NSLICE, FNCHUNK), HTHREADS, 0, stream>>>(row, col, dis, offsets,
                                                                    part_col, csr, E);

    // NC=2 grids: 196 panels x 2 col-blocks, swizzle needs grid multiple of 16 -> 400 (guarded)
    const int G2 = 400;
    // h = relu(x @ W_feat + b_feat) -> fp16
    mfma_gemm_kernel<1, 1, 2, 0><<<G2, 512, 0, stream>>>(
        x_hi, nullptr, nullptr, WTf_hi, b_feat,
        nullptr, h_hi, nullptr, nullptr, N, IN_CH, IN_CH, HID);

    const unsigned short* WThs[2] = {WT0_hi, WT1_hi};
    const float* bs[2]    = {b0, b1};
    const float* gs[2]    = {g0, g1};
    const float* betas[2] = {beta0, beta1};
    int prop_grid = (N + 3) / 4;
    for (int layer = 0; layer < 2; ++layer) {
        prop_kernel<<<prop_grid, 256, 0, stream>>>(h_hi, offsets, csr, agg1_hi, N);
        prop_kernel<<<prop_grid, 256, 0, stream>>>(agg1_hi, offsets, csr, agg2_hi, N);
        hipMemsetAsync(sums, 0, HID * 4, stream);
        hipMemsetAsync(sumsq, 0, HID * 4, stream);
        mfma_gemm_kernel<0, 0, 2, 1><<<G2, 512, 0, stream>>>(
            h_hi, agg1_hi, agg2_hi, WThs[layer], bs[layer],
            y, nullptr, sums, sumsq, N, 3 * HID, HID, HID);
        bnrelu_kernel<<<(N * HID / 4 + 255) / 256, 256, 0, stream>>>(y, sums, sumsq, gs[layer],
                                                                     betas[layer], h_hi, N);
    }

    mfma_gemm_kernel<0, 0, 1, 0><<<N_PAD / GBM, 512, 0, stream>>>(
        h_hi, nullptr, nullptr, WTc_hi, bc,
        out, nullptr, nullptr, nullptr, N, HID, HID, OUT_CH);
}

// Round 17
// 776.680 us; speedup vs baseline: 1.3016x; 1.0668x over previous
//
#include <hip/hip_runtime.h>

#define N_NODES 50000
#define N_PAD   50176            // 196 * 256
#define N_EDGES 1600000
#define IN_CH   512
#define HID     256
#define OUT_CH  40
#define BN_EPS  1e-5f

#define HCHUNK  6272             // hist: nodes per chunk (8 chunks, 49KB LDS)
#define NCHUNK  8
#define FCHUNK  12544            // fill: nodes per chunk (4 chunks, 49KB LDS)
#define FNCHUNK 4
#define NSLICE  32               // edge slices; E/NSLICE = 50000 exactly
#define HTHREADS 1024

typedef _Float16 f16x8 __attribute__((ext_vector_type(8)));
typedef __attribute__((ext_vector_type(8))) unsigned short u16x8;
typedef __attribute__((ext_vector_type(4))) float f32x4;

__device__ __forceinline__ unsigned short f2h_us(float f) {
    _Float16 h = (_Float16)f;
    return __builtin_bit_cast(unsigned short, h);
}
__device__ __forceinline__ float h2f(unsigned short u) {
    return (float)__builtin_bit_cast(_Float16, u);
}

// async global->LDS, 16B per lane; LDS dest is wave-uniform base + lane*16
__device__ __forceinline__ void gload_lds16(const void* gsrc, void* ldst) {
    __builtin_amdgcn_global_load_lds(
        (const __attribute__((address_space(1))) unsigned int*)gsrc,
        (__attribute__((address_space(3))) unsigned int*)ldst,
        16, 0, 0);
}

// ---------------- degree histograms via LDS privatization (no global atomics) ----------------
__global__ __launch_bounds__(HTHREADS)
void hist_kernel(const int* __restrict__ row, const int* __restrict__ col,
                 int* __restrict__ part_row, int* __restrict__ part_col, int E) {
    __shared__ int hr[HCHUNK];
    __shared__ int hc[HCHUNK];
    int s = blockIdx.x;        // edge slice
    int c = blockIdx.y;        // node chunk
    int base = c * HCHUNK;
    int t = threadIdx.x;
    for (int i = t; i < HCHUNK; i += HTHREADS) { hr[i] = 0; hc[i] = 0; }
    __syncthreads();
    int e0 = s * (E / NSLICE), e1 = e0 + E / NSLICE;
    for (int e = e0 + t; e < e1; e += HTHREADS) {
        int r = row[e], cc = col[e];
        unsigned lr = (unsigned)(r - base);
        unsigned lc = (unsigned)(cc - base);
        if (lr < HCHUNK) atomicAdd(&hr[lr], 1);
        if (lc < HCHUNK) atomicAdd(&hc[lc], 1);
    }
    __syncthreads();
    int* pr = part_row + (size_t)s * N_PAD + base;
    int* pc = part_col + (size_t)s * N_PAD + base;
    for (int i = t; i < HCHUNK; i += HTHREADS) { pr[i] = hr[i]; pc[i] = hc[i]; }
}

// merge + scan1 fused: deg_row -> dis; part_col -> per-node exclusive prefix over slices;
// per-256-node block sum -> bsums
__global__ void merge_scan1_kernel(const int* __restrict__ part_row, int* __restrict__ part_col,
                                   float* __restrict__ dis, int* __restrict__ deg_col,
                                   int* __restrict__ bsums, int n) {
    __shared__ int sd[256];
    int t = threadIdx.x;
    int i = blockIdx.x * 256 + t;
    int run = 0;
    if (i < n) {
        int dr = 0;
        #pragma unroll
        for (int s = 0; s < NSLICE; ++s)
            dr += part_row[(size_t)s * N_PAD + i];
        #pragma unroll
        for (int s = 0; s < NSLICE; ++s) {
            int cnt = part_col[(size_t)s * N_PAD + i];
            part_col[(size_t)s * N_PAD + i] = run;   // exclusive prefix
            run += cnt;
        }
        dis[i] = rsqrtf((float)max(dr, 1));
        deg_col[i] = run;
    }
    sd[t] = (i < n) ? run : 0;
    __syncthreads();
    for (int o = 128; o > 0; o >>= 1) {
        if (t < o) sd[t] += sd[t + o];
        __syncthreads();
    }
    if (t == 0) bsums[blockIdx.x] = sd[0];
}

__global__ void scan2_kernel(int* __restrict__ bsums, int nb) {   // 1 block, 256 threads
    __shared__ int sd[256];
    int t = threadIdx.x;
    int v = (t < nb) ? bsums[t] : 0;
    sd[t] = v;
    __syncthreads();
    for (int o = 1; o < 256; o <<= 1) {
        int u = (t >= o) ? sd[t - o] : 0;
        __syncthreads();
        sd[t] += u;
        __syncthreads();
    }
    if (t < nb) bsums[t] = sd[t] - v;   // exclusive
}

__global__ void scan3_kernel(const int* __restrict__ deg, const int* __restrict__ bsums,
                             int* __restrict__ offsets, int n) {
    __shared__ int sd[256];
    int t = threadIdx.x;
    int i = blockIdx.x * 256 + t;
    sd[t] = (i < n) ? deg[i] : 0;
    __syncthreads();
    for (int o = 1; o < 256; o <<= 1) {
        int u = (t >= o) ? sd[t - o] : 0;
        __syncthreads();
        sd[t] += u;
        __syncthreads();
    }
    if (i < n) offsets[i + 1] = bsums[blockIdx.x] + sd[t];
    if (i == 0) offsets[0] = 0;
}

// ---------------- CSR fill, chunked: LDS cursors + precomputed slice offsets (no global atomics) ----
__global__ __launch_bounds__(HTHREADS)
void fill_csr_kernel(const int* __restrict__ row, const int* __restrict__ col,
                     const float* __restrict__ dis, const int* __restrict__ offsets,
                     const int* __restrict__ part_col, int2* __restrict__ csr, int E) {
    __shared__ int cur[FCHUNK];
    int s = blockIdx.x;        // edge slice
    int c = blockIdx.y;        // node chunk
    int base = c * FCHUNK;
    int t = threadIdx.x;
    for (int i = t; i < FCHUNK; i += HTHREADS) cur[i] = 0;
    __syncthreads();
    int e0 = s * (E / NSLICE), e1 = e0 + E / NSLICE;
    for (int e = e0 + t; e < e1; e += HTHREADS) {
        int r = row[e], cc = col[e];
        unsigned lc = (unsigned)(cc - base);
        if (lc < FCHUNK) {
            int pos = atomicAdd(&cur[lc], 1);
            int idx = offsets[cc] + part_col[(size_t)s * N_PAD + cc] + pos;
            csr[idx] = make_int2(r, __float_as_int(dis[r] * dis[cc]));
        }
    }
}

// ---------------- x -> fp16 convert ----------------
__global__ void convert_x_kernel(const float* __restrict__ x, unsigned short* __restrict__ xhi,
                                 int n4) {
    int i = blockIdx.x * blockDim.x + threadIdx.x;
    if (i < n4) {
        float4 v = ((const float4*)x)[i];
        float r[4] = {v.x, v.y, v.z, v.w};
        ushort4 hs;
        unsigned short* hp = (unsigned short*)&hs;
        #pragma unroll
        for (int j = 0; j < 4; ++j) hp[j] = f2h_us(r[j]);
        ((ushort4*)xhi)[i] = hs;
    }
}

// ---------------- propagation (full-row fp16 gather, 8-deep MLP; hi-only output) ----------------
__global__ void prop_kernel(const unsigned short* __restrict__ hsrc,
                            const int* __restrict__ offsets,
                            const int2* __restrict__ csr,
                            unsigned short* __restrict__ Ohi, int n) {
    int node = blockIdx.x * 4 + (threadIdx.x >> 6);
    if (node >= n) return;
    int lane = threadIdx.x & 63;
    int half = lane >> 5;
    int cl   = lane & 31;           // 16B chunk id within the 512B row
    int beg = offsets[node], end = offsets[node + 1];
    float acc[8] = {0.f, 0.f, 0.f, 0.f, 0.f, 0.f, 0.f, 0.f};
    for (int i = beg; i < end; i += 16) {
        float w[8];
        int s[8];
        #pragma unroll
        for (int u = 0; u < 8; ++u) {
            int iu = i + 2 * u + half;
            int2 rec = csr[min(iu, end - 1)];
            w[u] = (iu < end) ? __int_as_float(rec.y) : 0.f;
            s[u] = rec.x;
        }
        u16x8 v[8];
        #pragma unroll
        for (int u = 0; u < 8; ++u)
            v[u] = *(const u16x8*)(hsrc + (size_t)s[u] * HID + cl * 8);
        #pragma unroll
        for (int u = 0; u < 8; ++u)
            #pragma unroll
            for (int j = 0; j < 8; ++j)
                acc[j] += w[u] * h2f((unsigned short)v[u][j]);
    }
    #pragma unroll
    for (int j = 0; j < 8; ++j) acc[j] += __shfl_xor(acc[j], 32);
    if (half == 0) {
        u16x8 ov;
        #pragma unroll
        for (int j = 0; j < 8; ++j) ov[j] = f2h_us(acc[j]);
        *(u16x8*)(Ohi + (size_t)node * HID + cl * 8) = ov;
    }
}

// ---------------- tiled transpose -> single fp16 plane: src[R][C] -> dst[C][R] ----------------
__global__ void transpose_half_kernel(const float* __restrict__ src,
                                      unsigned short* __restrict__ dhi, int R, int C) {
    __shared__ float tile[32][33];
    int c0 = blockIdx.x * 32, r0 = blockIdx.y * 32;
    int tx = threadIdx.x, ty = threadIdx.y;   // block (32, 8)
    #pragma unroll
    for (int i = 0; i < 32; i += 8) {
        int r = r0 + ty + i, c = c0 + tx;
        tile[ty + i][tx] = (r < R && c < C) ? src[(size_t)r * C + c] : 0.f;
    }
    __syncthreads();
    #pragma unroll
    for (int i = 0; i < 32; i += 8) {
        int c = c0 + ty + i, r = r0 + tx;
        if (c < C && r < R) dhi[(size_t)c * R + r] = f2h_us(tile[tx][ty + i]);
    }
}

// ---------------- MFMA GEMM (fp16, single-plane A): 256x128 tile, 8 waves, 2-phase dbuf ------
#define GBM 256
#define GBN 128
#define GBK 32

// ACT: relu; OUTMODE: 0 = fp32 C, 1 = fp16 C; NC: column blocks; STATS: fused BN colstats
template<int ACT, int OUTMODE, int NC, int STATS>
__global__ __launch_bounds__(512)
void mfma_gemm_kernel(const unsigned short* __restrict__ A0h,
                      const unsigned short* __restrict__ A1h,
                      const unsigned short* __restrict__ A2h,
                      const unsigned short* __restrict__ Wh,
                      const float* __restrict__ bvec,
                      float* __restrict__ C, unsigned short* __restrict__ Chi,
                      float* __restrict__ bn_sums, float* __restrict__ bn_sumsq,
                      int M, int K, int seg, int Kout) {
    // [buf][kgroup(4)][row][8 f16]: A 16KB/buf, B 8KB/buf -> 48KB total (3 blocks/CU)
    __shared__ __attribute__((aligned(16))) unsigned short As_hi[2][4 * GBM * 8];
    __shared__ __attribute__((aligned(16))) unsigned short Bs_hi[2][4 * GBN * 8];

    int tid  = threadIdx.x;
    int lane = tid & 63;
    int w    = tid >> 6;                   // wave id 0..7
    int wm   = w & 3, wn = w >> 2;         // 4x2 waves, 64x64 output each
    int kg   = lane >> 4, lr = lane & 15;  // fragment lane decomposition
    int kgq  = w & 3, hf = w >> 2;         // staging role: kgroup + half

    int bid = blockIdx.x, p, c;
    if (NC == 2) {
        p = ((bid >> 4) << 3) + (bid & 7);
        c = (bid >> 3) & 1;
        if (p >= N_PAD / GBM) return;      // grid padded to multiple of 16
    } else { p = bid; c = 0; }
    int bm = p * GBM, bn = c * GBN;

    f32x4 acc[4][4];
    #pragma unroll
    for (int i = 0; i < 4; ++i)
        #pragma unroll
        for (int j = 0; j < 4; ++j)
            acc[i][j] = (f32x4){0.f, 0.f, 0.f, 0.f};

    // stage: 2 A + 1 B gload_lds per wave
    auto STAGE = [&](int buf, int k0) {
        const unsigned short *Aph; int kl0;
        if (k0 < seg)          { Aph = A0h; kl0 = k0; }
        else if (k0 < 2 * seg) { Aph = A1h; kl0 = k0 - seg; }
        else                   { Aph = A2h; kl0 = k0 - 2 * seg; }
        size_t rA = (size_t)64 * seg;
        const unsigned short* a_h = Aph + (size_t)(bm + hf * 128 + lane) * seg + kl0 + kgq * 8;
        gload_lds16(a_h,      &As_hi[buf][(kgq * GBM + hf * 128)      * 8]);
        gload_lds16(a_h + rA, &As_hi[buf][(kgq * GBM + hf * 128 + 64) * 8]);
        const unsigned short* b_h = Wh + (size_t)(bn + hf * 64 + lane) * K + k0 + kgq * 8;
        gload_lds16(b_h,      &Bs_hi[buf][(kgq * GBN + hf * 64)       * 8]);
    };

    int nt = K / GBK;
    STAGE(0, 0);
    asm volatile("s_waitcnt vmcnt(0)" ::: "memory");
    __builtin_amdgcn_s_barrier();
    __builtin_amdgcn_sched_barrier(0);

    for (int t = 0; t < nt; ++t) {
        int cur = t & 1;
        if (t + 1 < nt) STAGE(cur ^ 1, (t + 1) * GBK);   // overlaps this step's compute

        int abase = (kg * GBM + wm * 64 + lr) * 8;
        int bbase = (kg * GBN + wn * 64 + lr) * 8;
        f16x8 ah[4], bh[4];
        #pragma unroll
        for (int mf = 0; mf < 4; ++mf)
            ah[mf] = *(const f16x8*)&As_hi[cur][abase + mf * 16 * 8];
        #pragma unroll
        for (int nf = 0; nf < 4; ++nf)
            bh[nf] = *(const f16x8*)&Bs_hi[cur][bbase + nf * 16 * 8];
        #pragma unroll
        for (int mf = 0; mf < 4; ++mf)
            #pragma unroll
            for (int nf = 0; nf < 4; ++nf)
                acc[mf][nf] = __builtin_amdgcn_mfma_f32_16x16x32_f16(ah[mf], bh[nf], acc[mf][nf], 0, 0, 0);

        asm volatile("s_waitcnt vmcnt(0)" ::: "memory");  // next tile landed
        __builtin_amdgcn_s_barrier();                     // all waves done reading buf cur
        __builtin_amdgcn_sched_barrier(0);
    }

    // ---- epilogue: C/D layout col = lane&15, row = (lane>>4)*4 + reg ----
    #pragma unroll
    for (int nf = 0; nf < 4; ++nf) {
        int col = bn + wn * 64 + nf * 16 + lr;
        if (col >= Kout) continue;
        float bv = bvec[col];
        float s1 = 0.f, s2 = 0.f;
        #pragma unroll
        for (int mf = 0; mf < 4; ++mf) {
            #pragma unroll
            for (int i = 0; i < 4; ++i) {
                int rw = bm + wm * 64 + mf * 16 + kg * 4 + i;
                if (rw < M) {
                    float v = acc[mf][nf][i] + bv;
                    if (ACT == 1) v = fmaxf(v, 0.f);
                    if (STATS) { s1 += v; s2 += v * v; }
                    if (OUTMODE == 0) {
                        C[(size_t)rw * Kout + col] = v;
                    } else {
                        Chi[(size_t)rw * Kout + col] = f2h_us(v);
                    }
                }
            }
        }
        if (STATS) {
            s1 += __shfl_xor(s1, 16); s1 += __shfl_xor(s1, 32);
            s2 += __shfl_xor(s2, 16); s2 += __shfl_xor(s2, 32);
            if (kg == 0) {
                atomicAdd(&bn_sums[col], s1);
                atomicAdd(&bn_sumsq[col], s2);
            }
        }
    }
}

__global__ void bnrelu_kernel(const float* __restrict__ y, const float* __restrict__ sums,
                              const float* __restrict__ sumsq, const float* __restrict__ g,
                              const float* __restrict__ beta,
                              unsigned short* __restrict__ Hhi, int M) {
    int idx = blockIdx.x * blockDim.x + threadIdx.x;   // group of 4 channels
    if (idx < M * HID / 4) {
        int col0 = (idx * 4) & (HID - 1);
        float4 v = ((const float4*)y)[idx];
        float invM = 1.0f / (float)M;
        float r[4] = {v.x, v.y, v.z, v.w};
        ushort4 hs;
        unsigned short* hp = (unsigned short*)&hs;
        #pragma unroll
        for (int j = 0; j < 4; ++j) {
            int col = col0 + j;
            float mean = sums[col] * invM;
            float var  = fmaxf(sumsq[col] * invM - mean * mean, 0.f);
            float o = (r[j] - mean) * rsqrtf(var + BN_EPS) * g[col] + beta[col];
            o = fmaxf(o, 0.f);
            hp[j] = f2h_us(o);
        }
        ((ushort4*)Hhi)[idx] = hs;
    }
}

extern "C" void kernel_launch(void* const* d_in, const int* in_sizes, int n_in,
                              void* d_out, int out_size, void* d_ws, size_t ws_size,
                              hipStream_t stream) {
    const float* x      = (const float*)d_in[0];
    const int*   ei     = (const int*)d_in[1];
    const float* W_feat = (const float*)d_in[2];
    const float* b_feat = (const float*)d_in[3];
    const float* W0     = (const float*)d_in[4];
    const float* b0     = (const float*)d_in[5];
    const float* g0     = (const float*)d_in[6];
    const float* beta0  = (const float*)d_in[7];
    const float* W1     = (const float*)d_in[8];
    const float* b1     = (const float*)d_in[9];
    const float* g1     = (const float*)d_in[10];
    const float* beta1  = (const float*)d_in[11];
    const float* Wc     = (const float*)d_in[12];
    const float* bc     = (const float*)d_in[13];
    float* out = (float*)d_out;

    const int N = N_NODES, E = N_EDGES;
    const int* row = ei;
    const int* col = ei + E;

    // workspace carve-up
    char* ws = (char*)d_ws;
    size_t off = 0;
    auto alloc = [&](size_t bytes) -> void* {
        void* p = ws + off;
        off = (off + bytes + 255) & ~(size_t)255;
        return p;
    };
    int*   deg_col  = (int*)  alloc(N * 4);
    int*   offsets  = (int*)  alloc((N + 1) * 4);
    int*   bsums    = (int*)  alloc(256 * 4);
    float* dis      = (float*)alloc(N * 4);
    int*   part_row = (int*)  alloc((size_t)NSLICE * N_PAD * 4);
    int*   part_col = (int*)  alloc((size_t)NSLICE * N_PAD * 4);
    int2*  csr      = (int2*) alloc((size_t)E * 8);
    unsigned short* x_hi    = (unsigned short*)alloc((size_t)N_PAD * IN_CH * 2);
    unsigned short* h_hi    = (unsigned short*)alloc((size_t)N_PAD * HID * 2);
    unsigned short* agg1_hi = (unsigned short*)alloc((size_t)N_PAD * HID * 2);
    float*          y       = (float*)alloc((size_t)N_PAD * HID * 4);
    // lifetime aliasing: x_hi is dead after the feat GEMM; reuse the region
    unsigned short* agg2_hi = x_hi;
    float* sums     = (float*)alloc(HID * 4);
    float* sumsq    = (float*)alloc(HID * 4);
    unsigned short* WTf_hi = (unsigned short*)alloc((size_t)HID * IN_CH * 2);
    unsigned short* WT0_hi = (unsigned short*)alloc((size_t)HID * 3 * HID * 2);
    unsigned short* WT1_hi = (unsigned short*)alloc((size_t)HID * 3 * HID * 2);
    unsigned short* WTc_hi = (unsigned short*)alloc((size_t)128 * HID * 2);   // 40 rows padded to 128

    hipMemsetAsync(WTc_hi, 0, (size_t)128 * HID * 2, stream);

    // operand pre-converts (independent of CSR build)
    convert_x_kernel<<<(N * IN_CH / 4 + 255) / 256, 256, 0, stream>>>(x, x_hi, N * IN_CH / 4);
    dim3 tb(32, 8);
    transpose_half_kernel<<<dim3(HID / 32, IN_CH / 32), tb, 0, stream>>>(W_feat, WTf_hi, IN_CH, HID);
    transpose_half_kernel<<<dim3(HID / 32, 3 * HID / 32), tb, 0, stream>>>(W0, WT0_hi, 3 * HID, HID);
    transpose_half_kernel<<<dim3(HID / 32, 3 * HID / 32), tb, 0, stream>>>(W1, WT1_hi, 3 * HID, HID);
    transpose_half_kernel<<<dim3((OUT_CH + 31) / 32, HID / 32), tb, 0, stream>>>(Wc, WTc_hi, HID, OUT_CH);

    // degree histograms (LDS-privatized, atomic-free globally)
    hist_kernel<<<dim3(NSLICE, NCHUNK), HTHREADS, 0, stream>>>(row, col, part_row, part_col, E);

    const int NB_SCAN = (N + 255) / 256;   // 196
    merge_scan1_kernel<<<NB_SCAN, 256, 0, stream>>>(part_row, part_col, dis, deg_col, bsums, N);
    scan2_kernel<<<1, 256, 0, stream>>>(bsums, NB_SCAN);
    scan3_kernel<<<NB_SCAN, 256, 0, stream>>>(deg_col, bsums, offsets, N);
    // chunked fill: LDS cursors + per-(slice,node) offsets from hist prefix
    fill_csr_kernel<<<dim3(NSLICE, FNCHUNK), HTHREADS, 0, stream>>>(row, col, dis, offsets,
                                                                    part_col, csr, E);

    // NC=2 grids: 196 panels x 2 col-blocks, swizzle needs grid multiple of 16 -> 400 (guarded)
    const int G2 = 400;
    // h = relu(x @ W_feat + b_feat) -> fp16
    mfma_gemm_kernel<1, 1, 2, 0><<<G2, 512, 0, stream>>>(
        x_hi, nullptr, nullptr, WTf_hi, b_feat,
        nullptr, h_hi, nullptr, nullptr, N, IN_CH, IN_CH, HID);

    const unsigned short* WThs[2] = {WT0_hi, WT1_hi};
    const float* bs[2]    = {b0, b1};
    const float* gs[2]    = {g0, g1};
    const float* betas[2] = {beta0, beta1};
    int prop_grid = (N + 3) / 4;
    for (int layer = 0; layer < 2; ++layer) {
        prop_kernel<<<prop_grid, 256, 0, stream>>>(h_hi, offsets, csr, agg1_hi, N);
        prop_kernel<<<prop_grid, 256, 0, stream>>>(agg1_hi, offsets, csr, agg2_hi, N);
        hipMemsetAsync(sums, 0, HID * 4, stream);
        hipMemsetAsync(sumsq, 0, HID * 4, stream);
        mfma_gemm_kernel<0, 0, 2, 1><<<G2, 512, 0, stream>>>(
            h_hi, agg1_hi, agg2_hi, WThs[layer], bs[layer],
            y, nullptr, sums, sumsq, N, 3 * HID, HID, HID);
        bnrelu_kernel<<<(N * HID / 4 + 255) / 256, 256, 0, stream>>>(y, sums, sumsq, gs[layer],
                                                                     betas[layer], h_hi, N);
    }

    mfma_gemm_kernel<0, 0, 1, 0><<<N_PAD / GBM, 512, 0, stream>>>(
        h_hi, nullptr, nullptr, WTc_hi, bc,
        out, nullptr, nullptr, nullptr, N, HID, HID, OUT_CH);
}

// Round 18
// 766.887 us; speedup vs baseline: 1.3182x; 1.0128x over previous
//
#include <hip/hip_runtime.h>

#define N_NODES 50000
#define N_PAD   50176            // 196 * 256
#define N_EDGES 1600000
#define IN_CH   512
#define HID     256
#define OUT_CH  40
#define BN_EPS  1e-5f

#define HCHUNK  6272             // hist: nodes per chunk (8 chunks, 49KB LDS)
#define NCHUNK  8
#define FCHUNK  12544            // fill: nodes per chunk (4 chunks, 49KB LDS)
#define FNCHUNK 4
#define NSLICE  32               // edge slices; E/NSLICE = 50000 exactly
#define HTHREADS 1024

typedef _Float16 f16x8 __attribute__((ext_vector_type(8)));
typedef __attribute__((ext_vector_type(8))) unsigned short u16x8;
typedef __attribute__((ext_vector_type(4))) float f32x4;
typedef int i32x2 __attribute__((ext_vector_type(2)));

__device__ __forceinline__ unsigned short f2h_us(float f) {
    _Float16 h = (_Float16)f;
    return __builtin_bit_cast(unsigned short, h);
}
__device__ __forceinline__ float h2f(unsigned short u) {
    return (float)__builtin_bit_cast(_Float16, u);
}

// async global->LDS, 16B per lane; LDS dest is wave-uniform base + lane*16
__device__ __forceinline__ void gload_lds16(const void* gsrc, void* ldst) {
    __builtin_amdgcn_global_load_lds(
        (const __attribute__((address_space(1))) unsigned int*)gsrc,
        (__attribute__((address_space(3))) unsigned int*)ldst,
        16, 0, 0);
}

// ---------------- degree histograms via LDS privatization (no global atomics) ----------------
__global__ __launch_bounds__(HTHREADS)
void hist_kernel(const int* __restrict__ row, const int* __restrict__ col,
                 int* __restrict__ part_row, int* __restrict__ part_col, int E) {
    __shared__ int hr[HCHUNK];
    __shared__ int hc[HCHUNK];
    int s = blockIdx.x;        // edge slice
    int c = blockIdx.y;        // node chunk
    int base = c * HCHUNK;
    int t = threadIdx.x;
    for (int i = t; i < HCHUNK; i += HTHREADS) { hr[i] = 0; hc[i] = 0; }
    __syncthreads();
    int e0 = s * (E / NSLICE), e1 = e0 + E / NSLICE;
    for (int e = e0 + t; e < e1; e += HTHREADS) {
        int r = row[e], cc = col[e];
        unsigned lr = (unsigned)(r - base);
        unsigned lc = (unsigned)(cc - base);
        if (lr < HCHUNK) atomicAdd(&hr[lr], 1);
        if (lc < HCHUNK) atomicAdd(&hc[lc], 1);
    }
    __syncthreads();
    int* pr = part_row + (size_t)s * N_PAD + base;
    int* pc = part_col + (size_t)s * N_PAD + base;
    for (int i = t; i < HCHUNK; i += HTHREADS) { pr[i] = hr[i]; pc[i] = hc[i]; }
}

// merge + scan1 fused: deg_row -> dis; part_col -> per-node exclusive prefix over slices;
// per-256-node block sum -> bsums
__global__ void merge_scan1_kernel(const int* __restrict__ part_row, int* __restrict__ part_col,
                                   float* __restrict__ dis, int* __restrict__ deg_col,
                                   int* __restrict__ bsums, int n) {
    __shared__ int sd[256];
    int t = threadIdx.x;
    int i = blockIdx.x * 256 + t;
    int run = 0;
    if (i < n) {
        int dr = 0;
        #pragma unroll
        for (int s = 0; s < NSLICE; ++s)
            dr += part_row[(size_t)s * N_PAD + i];
        #pragma unroll
        for (int s = 0; s < NSLICE; ++s) {
            int cnt = part_col[(size_t)s * N_PAD + i];
            part_col[(size_t)s * N_PAD + i] = run;   // exclusive prefix
            run += cnt;
        }
        dis[i] = rsqrtf((float)max(dr, 1));
        deg_col[i] = run;
    }
    sd[t] = (i < n) ? run : 0;
    __syncthreads();
    for (int o = 128; o > 0; o >>= 1) {
        if (t < o) sd[t] += sd[t + o];
        __syncthreads();
    }
    if (t == 0) bsums[blockIdx.x] = sd[0];
}

__global__ void scan2_kernel(int* __restrict__ bsums, int nb) {   // 1 block, 256 threads
    __shared__ int sd[256];
    int t = threadIdx.x;
    int v = (t < nb) ? bsums[t] : 0;
    sd[t] = v;
    __syncthreads();
    for (int o = 1; o < 256; o <<= 1) {
        int u = (t >= o) ? sd[t - o] : 0;
        __syncthreads();
        sd[t] += u;
        __syncthreads();
    }
    if (t < nb) bsums[t] = sd[t] - v;   // exclusive
}

__global__ void scan3_kernel(const int* __restrict__ deg, const int* __restrict__ bsums,
                             int* __restrict__ offsets, int n) {
    __shared__ int sd[256];
    int t = threadIdx.x;
    int i = blockIdx.x * 256 + t;
    sd[t] = (i < n) ? deg[i] : 0;
    __syncthreads();
    for (int o = 1; o < 256; o <<= 1) {
        int u = (t >= o) ? sd[t - o] : 0;
        __syncthreads();
        sd[t] += u;
        __syncthreads();
    }
    if (i < n) offsets[i + 1] = bsums[blockIdx.x] + sd[t];
    if (i == 0) offsets[0] = 0;
}

// ---------------- CSR fill, chunked: LDS cursors + precomputed slice offsets (no global atomics) ----
__global__ __launch_bounds__(HTHREADS)
void fill_csr_kernel(const int* __restrict__ row, const int* __restrict__ col,
                     const float* __restrict__ dis, const int* __restrict__ offsets,
                     const int* __restrict__ part_col, int2* __restrict__ csr, int E) {
    __shared__ int cur[FCHUNK];
    int s = blockIdx.x;        // edge slice
    int c = blockIdx.y;        // node chunk
    int base = c * FCHUNK;
    int t = threadIdx.x;
    for (int i = t; i < FCHUNK; i += HTHREADS) cur[i] = 0;
    __syncthreads();
    int e0 = s * (E / NSLICE), e1 = e0 + E / NSLICE;
    for (int e = e0 + t; e < e1; e += HTHREADS) {
        int r = row[e], cc = col[e];
        unsigned lc = (unsigned)(cc - base);
        if (lc < FCHUNK) {
            int pos = atomicAdd(&cur[lc], 1);
            int idx = offsets[cc] + part_col[(size_t)s * N_PAD + cc] + pos;
            csr[idx] = make_int2(r, __float_as_int(dis[r] * dis[cc]));
        }
    }
}

// ---------------- x -> fp16 convert ----------------
__global__ void convert_x_kernel(const float* __restrict__ x, unsigned short* __restrict__ xhi,
                                 int n4) {
    int i = blockIdx.x * blockDim.x + threadIdx.x;
    if (i < n4) {
        float4 v = ((const float4*)x)[i];
        float r[4] = {v.x, v.y, v.z, v.w};
        ushort4 hs;
        unsigned short* hp = (unsigned short*)&hs;
        #pragma unroll
        for (int j = 0; j < 4; ++j) hp[j] = f2h_us(r[j]);
        ((ushort4*)xhi)[i] = hs;
    }
}

// ---------------- propagation (full-row fp16 gather, 8-deep MLP; hi-only output) ----------------
// edge records + output use non-temporal hints to preserve L2 for the gather table
__global__ void prop_kernel(const unsigned short* __restrict__ hsrc,
                            const int* __restrict__ offsets,
                            const int2* __restrict__ csr,
                            unsigned short* __restrict__ Ohi, int n) {
    int node = blockIdx.x * 4 + (threadIdx.x >> 6);
    if (node >= n) return;
    int lane = threadIdx.x & 63;
    int half = lane >> 5;
    int cl   = lane & 31;           // 16B chunk id within the 512B row
    int beg = offsets[node], end = offsets[node + 1];
    float acc[8] = {0.f, 0.f, 0.f, 0.f, 0.f, 0.f, 0.f, 0.f};
    for (int i = beg; i < end; i += 16) {
        float w[8];
        int s[8];
        #pragma unroll
        for (int u = 0; u < 8; ++u) {
            int iu = i + 2 * u + half;
            i32x2 rec = __builtin_nontemporal_load((const i32x2*)(csr + min(iu, end - 1)));
            w[u] = (iu < end) ? __int_as_float(rec[1]) : 0.f;
            s[u] = rec[0];
        }
        u16x8 v[8];
        #pragma unroll
        for (int u = 0; u < 8; ++u)
            v[u] = *(const u16x8*)(hsrc + (size_t)s[u] * HID + cl * 8);
        #pragma unroll
        for (int u = 0; u < 8; ++u)
            #pragma unroll
            for (int j = 0; j < 8; ++j)
                acc[j] += w[u] * h2f((unsigned short)v[u][j]);
    }
    #pragma unroll
    for (int j = 0; j < 8; ++j) acc[j] += __shfl_xor(acc[j], 32);
    if (half == 0) {
        u16x8 ov;
        #pragma unroll
        for (int j = 0; j < 8; ++j) ov[j] = f2h_us(acc[j]);
        __builtin_nontemporal_store(ov, (u16x8*)(Ohi + (size_t)node * HID + cl * 8));
    }
}

// ---------------- tiled transpose -> single fp16 plane: src[R][C] -> dst[C][R] ----------------
__global__ void transpose_half_kernel(const float* __restrict__ src,
                                      unsigned short* __restrict__ dhi, int R, int C) {
    __shared__ float tile[32][33];
    int c0 = blockIdx.x * 32, r0 = blockIdx.y * 32;
    int tx = threadIdx.x, ty = threadIdx.y;   // block (32, 8)
    #pragma unroll
    for (int i = 0; i < 32; i += 8) {
        int r = r0 + ty + i, c = c0 + tx;
        tile[ty + i][tx] = (r < R && c < C) ? src[(size_t)r * C + c] : 0.f;
    }
    __syncthreads();
    #pragma unroll
    for (int i = 0; i < 32; i += 8) {
        int c = c0 + ty + i, r = r0 + tx;
        if (c < C && r < R) dhi[(size_t)c * R + r] = f2h_us(tile[tx][ty + i]);
    }
}

// ---------------- MFMA GEMM (fp16, single-plane A): 256x128 tile, 8 waves, 2-phase dbuf ------
#define GBM 256
#define GBN 128
#define GBK 32

// ACT: relu; OUTMODE: 0 = fp32 C, 1 = fp16 C; NC: column blocks; STATS: fused BN colstats
template<int ACT, int OUTMODE, int NC, int STATS>
__global__ __launch_bounds__(512)
void mfma_gemm_kernel(const unsigned short* __restrict__ A0h,
                      const unsigned short* __restrict__ A1h,
                      const unsigned short* __restrict__ A2h,
                      const unsigned short* __restrict__ Wh,
                      const float* __restrict__ bvec,
                      float* __restrict__ C, unsigned short* __restrict__ Chi,
                      float* __restrict__ bn_sums, float* __restrict__ bn_sumsq,
                      int M, int K, int seg, int Kout) {
    // [buf][kgroup(4)][row][8 f16]: A 16KB/buf, B 8KB/buf -> 48KB total (3 blocks/CU)
    __shared__ __attribute__((aligned(16))) unsigned short As_hi[2][4 * GBM * 8];
    __shared__ __attribute__((aligned(16))) unsigned short Bs_hi[2][4 * GBN * 8];

    int tid  = threadIdx.x;
    int lane = tid & 63;
    int w    = tid >> 6;                   // wave id 0..7
    int wm   = w & 3, wn = w >> 2;         // 4x2 waves, 64x64 output each
    int kg   = lane >> 4, lr = lane & 15;  // fragment lane decomposition
    int kgq  = w & 3, hf = w >> 2;         // staging role: kgroup + half

    int bid = blockIdx.x, p, c;
    if (NC == 2) {
        p = ((bid >> 4) << 3) + (bid & 7);
        c = (bid >> 3) & 1;
        if (p >= N_PAD / GBM) return;      // grid padded to multiple of 16
    } else { p = bid; c = 0; }
    int bm = p * GBM, bn = c * GBN;

    f32x4 acc[4][4];
    #pragma unroll
    for (int i = 0; i < 4; ++i)
        #pragma unroll
        for (int j = 0; j < 4; ++j)
            acc[i][j] = (f32x4){0.f, 0.f, 0.f, 0.f};

    // stage: 2 A + 1 B gload_lds per wave
    auto STAGE = [&](int buf, int k0) {
        const unsigned short *Aph; int kl0;
        if (k0 < seg)          { Aph = A0h; kl0 = k0; }
        else if (k0 < 2 * seg) { Aph = A1h; kl0 = k0 - seg; }
        else                   { Aph = A2h; kl0 = k0 - 2 * seg; }
        size_t rA = (size_t)64 * seg;
        const unsigned short* a_h = Aph + (size_t)(bm + hf * 128 + lane) * seg + kl0 + kgq * 8;
        gload_lds16(a_h,      &As_hi[buf][(kgq * GBM + hf * 128)      * 8]);
        gload_lds16(a_h + rA, &As_hi[buf][(kgq * GBM + hf * 128 + 64) * 8]);
        const unsigned short* b_h = Wh + (size_t)(bn + hf * 64 + lane) * K + k0 + kgq * 8;
        gload_lds16(b_h,      &Bs_hi[buf][(kgq * GBN + hf * 64)       * 8]);
    };

    int nt = K / GBK;
    STAGE(0, 0);
    asm volatile("s_waitcnt vmcnt(0)" ::: "memory");
    __builtin_amdgcn_s_barrier();
    __builtin_amdgcn_sched_barrier(0);

    for (int t = 0; t < nt; ++t) {
        int cur = t & 1;
        if (t + 1 < nt) STAGE(cur ^ 1, (t + 1) * GBK);   // overlaps this step's compute

        int abase = (kg * GBM + wm * 64 + lr) * 8;
        int bbase = (kg * GBN + wn * 64 + lr) * 8;
        f16x8 ah[4], bh[4];
        #pragma unroll
        for (int mf = 0; mf < 4; ++mf)
            ah[mf] = *(const f16x8*)&As_hi[cur][abase + mf * 16 * 8];
        #pragma unroll
        for (int nf = 0; nf < 4; ++nf)
            bh[nf] = *(const f16x8*)&Bs_hi[cur][bbase + nf * 16 * 8];
        #pragma unroll
        for (int mf = 0; mf < 4; ++mf)
            #pragma unroll
            for (int nf = 0; nf < 4; ++nf)
                acc[mf][nf] = __builtin_amdgcn_mfma_f32_16x16x32_f16(ah[mf], bh[nf], acc[mf][nf], 0, 0, 0);

        asm volatile("s_waitcnt vmcnt(0)" ::: "memory");  // next tile landed
        __builtin_amdgcn_s_barrier();                     // all waves done reading buf cur
        __builtin_amdgcn_sched_barrier(0);
    }

    // ---- epilogue: C/D layout col = lane&15, row = (lane>>4)*4 + reg ----
    #pragma unroll
    for (int nf = 0; nf < 4; ++nf) {
        int col = bn + wn * 64 + nf * 16 + lr;
        if (col >= Kout) continue;
        float bv = bvec[col];
        float s1 = 0.f, s2 = 0.f;
        #pragma unroll
        for (int mf = 0; mf < 4; ++mf) {
            #pragma unroll
            for (int i = 0; i < 4; ++i) {
                int rw = bm + wm * 64 + mf * 16 + kg * 4 + i;
                if (rw < M) {
                    float v = acc[mf][nf][i] + bv;
                    if (ACT == 1) v = fmaxf(v, 0.f);
                    if (STATS) { s1 += v; s2 += v * v; }
                    if (OUTMODE == 0) {
                        C[(size_t)rw * Kout + col] = v;
                    } else {
                        Chi[(size_t)rw * Kout + col] = f2h_us(v);
                    }
                }
            }
        }
        if (STATS) {
            s1 += __shfl_xor(s1, 16); s1 += __shfl_xor(s1, 32);
            s2 += __shfl_xor(s2, 16); s2 += __shfl_xor(s2, 32);
            if (kg == 0) {
                atomicAdd(&bn_sums[col], s1);
                atomicAdd(&bn_sumsq[col], s2);
            }
        }
    }
}

// bnrelu: reads fp16 y, writes fp16 h
__global__ void bnrelu_kernel(const unsigned short* __restrict__ y, const float* __restrict__ sums,
                              const float* __restrict__ sumsq, const float* __restrict__ g,
                              const float* __restrict__ beta,
                              unsigned short* __restrict__ Hhi, int M) {
    int idx = blockIdx.x * blockDim.x + threadIdx.x;   // group of 4 channels
    if (idx < M * HID / 4) {
        int col0 = (idx * 4) & (HID - 1);
        ushort4 v = ((const ushort4*)y)[idx];
        unsigned short* vp = (unsigned short*)&v;
        float invM = 1.0f / (float)M;
        ushort4 hs;
        unsigned short* hp = (unsigned short*)&hs;
        #pragma unroll
        for (int j = 0; j < 4; ++j) {
            int col = col0 + j;
            float mean = sums[col] * invM;
            float var  = fmaxf(sumsq[col] * invM - mean * mean, 0.f);
            float o = (h2f(vp[j]) - mean) * rsqrtf(var + BN_EPS) * g[col] + beta[col];
            o = fmaxf(o, 0.f);
            hp[j] = f2h_us(o);
        }
        ((ushort4*)Hhi)[idx] = hs;
    }
}

extern "C" void kernel_launch(void* const* d_in, const int* in_sizes, int n_in,
                              void* d_out, int out_size, void* d_ws, size_t ws_size,
                              hipStream_t stream) {
    const float* x      = (const float*)d_in[0];
    const int*   ei     = (const int*)d_in[1];
    const float* W_feat = (const float*)d_in[2];
    const float* b_feat = (const float*)d_in[3];
    const float* W0     = (const float*)d_in[4];
    const float* b0     = (const float*)d_in[5];
    const float* g0     = (const float*)d_in[6];
    const float* beta0  = (const float*)d_in[7];
    const float* W1     = (const float*)d_in[8];
    const float* b1     = (const float*)d_in[9];
    const float* g1     = (const float*)d_in[10];
    const float* beta1  = (const float*)d_in[11];
    const float* Wc     = (const float*)d_in[12];
    const float* bc     = (const float*)d_in[13];
    float* out = (float*)d_out;

    const int N = N_NODES, E = N_EDGES;
    const int* row = ei;
    const int* col = ei + E;

    // workspace carve-up
    char* ws = (char*)d_ws;
    size_t off = 0;
    auto alloc = [&](size_t bytes) -> void* {
        void* p = ws + off;
        off = (off + bytes + 255) & ~(size_t)255;
        return p;
    };
    int*   deg_col  = (int*)  alloc(N * 4);
    int*   offsets  = (int*)  alloc((N + 1) * 4);
    int*   bsums    = (int*)  alloc(256 * 4);
    float* dis      = (float*)alloc(N * 4);
    int*   part_row = (int*)  alloc((size_t)NSLICE * N_PAD * 4);
    int*   part_col = (int*)  alloc((size_t)NSLICE * N_PAD * 4);
    int2*  csr      = (int2*) alloc((size_t)E * 8);
    unsigned short* x_hi    = (unsigned short*)alloc((size_t)N_PAD * IN_CH * 2);
    unsigned short* h_hi    = (unsigned short*)alloc((size_t)N_PAD * HID * 2);
    unsigned short* agg1_hi = (unsigned short*)alloc((size_t)N_PAD * HID * 2);
    // lifetime aliasing: x_hi (2 * N_PAD*HID ushorts) is dead after the feat GEMM
    unsigned short* agg2_hi = x_hi;                          // first half
    unsigned short* y_h     = x_hi + (size_t)N_PAD * HID;    // second half
    float* sums     = (float*)alloc(HID * 4);
    float* sumsq    = (float*)alloc(HID * 4);
    unsigned short* WTf_hi = (unsigned short*)alloc((size_t)HID * IN_CH * 2);
    unsigned short* WT0_hi = (unsigned short*)alloc((size_t)HID * 3 * HID * 2);
    unsigned short* WT1_hi = (unsigned short*)alloc((size_t)HID * 3 * HID * 2);
    unsigned short* WTc_hi = (unsigned short*)alloc((size_t)128 * HID * 2);   // 40 rows padded to 128

    hipMemsetAsync(WTc_hi, 0, (size_t)128 * HID * 2, stream);

    // operand pre-converts (independent of CSR build)
    convert_x_kernel<<<(N * IN_CH / 4 + 255) / 256, 256, 0, stream>>>(x, x_hi, N * IN_CH / 4);
    dim3 tb(32, 8);
    transpose_half_kernel<<<dim3(HID / 32, IN_CH / 32), tb, 0, stream>>>(W_feat, WTf_hi, IN_CH, HID);
    transpose_half_kernel<<<dim3(HID / 32, 3 * HID / 32), tb, 0, stream>>>(W0, WT0_hi, 3 * HID, HID);
    transpose_half_kernel<<<dim3(HID / 32, 3 * HID / 32), tb, 0, stream>>>(W1, WT1_hi, 3 * HID, HID);
    transpose_half_kernel<<<dim3((OUT_CH + 31) / 32, HID / 32), tb, 0, stream>>>(Wc, WTc_hi, HID, OUT_CH);

    // degree histograms (LDS-privatized, atomic-free globally)
    hist_kernel<<<dim3(NSLICE, NCHUNK), HTHREADS, 0, stream>>>(row, col, part_row, part_col, E);

    const int NB_SCAN = (N + 255) / 256;   // 196
    merge_scan1_kernel<<<NB_SCAN, 256, 0, stream>>>(part_row, part_col, dis, deg_col, bsums, N);
    scan2_kernel<<<1, 256, 0, stream>>>(bsums, NB_SCAN);
    scan3_kernel<<<NB_SCAN, 256, 0, stream>>>(deg_col, bsums, offsets, N);
    // chunked fill: LDS cursors + per-(slice,node) offsets from hist prefix
    fill_csr_kernel<<<dim3(NSLICE, FNCHUNK), HTHREADS, 0, stream>>>(row, col, dis, offsets,
                                                                    part_col, csr, E);

    // NC=2 grids: 196 panels x 2 col-blocks, swizzle needs grid multiple of 16 -> 400 (guarded)
    const int G2 = 400;
    // h = relu(x @ W_feat + b_feat) -> fp16
    mfma_gemm_kernel<1, 1, 2, 0><<<G2, 512, 0, stream>>>(
        x_hi, nullptr, nullptr, WTf_hi, b_feat,
        nullptr, h_hi, nullptr, nullptr, N, IN_CH, IN_CH, HID);

    const unsigned short* WThs[2] = {WT0_hi, WT1_hi};
    const float* bs[2]    = {b0, b1};
    const float* gs[2]    = {g0, g1};
    const float* betas[2] = {beta0, beta1};
    int prop_grid = (N + 3) / 4;
    for (int layer = 0; layer < 2; ++layer) {
        prop_kernel<<<prop_grid, 256, 0, stream>>>(h_hi, offsets, csr, agg1_hi, N);
        prop_kernel<<<prop_grid, 256, 0, stream>>>(agg1_hi, offsets, csr, agg2_hi, N);
        hipMemsetAsync(sums, 0, HID * 4, stream);
        hipMemsetAsync(sumsq, 0, HID * 4, stream);
        mfma_gemm_kernel<0, 1, 2, 1><<<G2, 512, 0, stream>>>(
            h_hi, agg1_hi, agg2_hi, WThs[layer], bs[layer],
            nullptr, y_h, sums, sumsq, N, 3 * HID, HID, HID);
        bnrelu_kernel<<<(N * HID / 4 + 255) / 256, 256, 0, stream>>>(y_h, sums, sumsq, gs[layer],
                                                                     betas[layer], h_hi, N);
    }

    mfma_gemm_kernel<0, 0, 1, 0><<<N_PAD / GBM, 512, 0, stream>>>(
        h_hi, nullptr, nullptr, WTc_hi, bc,
        out, nullptr, nullptr, nullptr, N, HID, HID, OUT_CH);
}

// Round 19
// 748.470 us; speedup vs baseline: 1.3506x; 1.0246x over previous
//
#include <hip/hip_runtime.h>

#define N_NODES 50000
#define N_PAD   50176            // 196 * 256
#define N_EDGES 1600000
#define IN_CH   512
#define HID     256
#define OUT_CH  40
#define BN_EPS  1e-5f

#define HCHUNK  6272             // hist: nodes per chunk (8 chunks, 49KB LDS)
#define NCHUNK  8
#define FCHUNK  12544            // fill: nodes per chunk (4 chunks, 49KB LDS)
#define FNCHUNK 4
#define NSLICE  32               // edge slices; E/NSLICE = 50000 exactly
#define HTHREADS 1024

typedef _Float16 f16x8 __attribute__((ext_vector_type(8)));
typedef __attribute__((ext_vector_type(8))) unsigned short u16x8;
typedef __attribute__((ext_vector_type(4))) float f32x4;

__device__ __forceinline__ unsigned short f2h_us(float f) {
    _Float16 h = (_Float16)f;
    return __builtin_bit_cast(unsigned short, h);
}
__device__ __forceinline__ float h2f(unsigned short u) {
    return (float)__builtin_bit_cast(_Float16, u);
}

// async global->LDS, 16B per lane; LDS dest is wave-uniform base + lane*16
__device__ __forceinline__ void gload_lds16(const void* gsrc, void* ldst) {
    __builtin_amdgcn_global_load_lds(
        (const __attribute__((address_space(1))) unsigned int*)gsrc,
        (__attribute__((address_space(3))) unsigned int*)ldst,
        16, 0, 0);
}

// ---------------- degree histograms via LDS privatization (no global atomics) ----------------
__global__ __launch_bounds__(HTHREADS)
void hist_kernel(const int* __restrict__ row, const int* __restrict__ col,
                 int* __restrict__ part_row, int* __restrict__ part_col, int E) {
    __shared__ int hr[HCHUNK];
    __shared__ int hc[HCHUNK];
    int s = blockIdx.x;        // edge slice
    int c = blockIdx.y;        // node chunk
    int base = c * HCHUNK;
    int t = threadIdx.x;
    for (int i = t; i < HCHUNK; i += HTHREADS) { hr[i] = 0; hc[i] = 0; }
    __syncthreads();
    int e0 = s * (E / NSLICE), e1 = e0 + E / NSLICE;
    for (int e = e0 + t; e < e1; e += HTHREADS) {
        int r = row[e], cc = col[e];
        unsigned lr = (unsigned)(r - base);
        unsigned lc = (unsigned)(cc - base);
        if (lr < HCHUNK) atomicAdd(&hr[lr], 1);
        if (lc < HCHUNK) atomicAdd(&hc[lc], 1);
    }
    __syncthreads();
    int* pr = part_row + (size_t)s * N_PAD + base;
    int* pc = part_col + (size_t)s * N_PAD + base;
    for (int i = t; i < HCHUNK; i += HTHREADS) { pr[i] = hr[i]; pc[i] = hc[i]; }
}

// merge + scan1 fused: deg_row -> dis; part_col -> per-node exclusive prefix over slices;
// per-256-node block sum -> bsums
__global__ void merge_scan1_kernel(const int* __restrict__ part_row, int* __restrict__ part_col,
                                   float* __restrict__ dis, int* __restrict__ deg_col,
                                   int* __restrict__ bsums, int n) {
    __shared__ int sd[256];
    int t = threadIdx.x;
    int i = blockIdx.x * 256 + t;
    int run = 0;
    if (i < n) {
        int dr = 0;
        #pragma unroll
        for (int s = 0; s < NSLICE; ++s)
            dr += part_row[(size_t)s * N_PAD + i];
        #pragma unroll
        for (int s = 0; s < NSLICE; ++s) {
            int cnt = part_col[(size_t)s * N_PAD + i];
            part_col[(size_t)s * N_PAD + i] = run;   // exclusive prefix
            run += cnt;
        }
        dis[i] = rsqrtf((float)max(dr, 1));
        deg_col[i] = run;
    }
    sd[t] = (i < n) ? run : 0;
    __syncthreads();
    for (int o = 128; o > 0; o >>= 1) {
        if (t < o) sd[t] += sd[t + o];
        __syncthreads();
    }
    if (t == 0) bsums[blockIdx.x] = sd[0];
}

__global__ void scan2_kernel(int* __restrict__ bsums, int nb) {   // 1 block, 256 threads
    __shared__ int sd[256];
    int t = threadIdx.x;
    int v = (t < nb) ? bsums[t] : 0;
    sd[t] = v;
    __syncthreads();
    for (int o = 1; o < 256; o <<= 1) {
        int u = (t >= o) ? sd[t - o] : 0;
        __syncthreads();
        sd[t] += u;
        __syncthreads();
    }
    if (t < nb) bsums[t] = sd[t] - v;   // exclusive
}

__global__ void scan3_kernel(const int* __restrict__ deg, const int* __restrict__ bsums,
                             int* __restrict__ offsets, int n) {
    __shared__ int sd[256];
    int t = threadIdx.x;
    int i = blockIdx.x * 256 + t;
    sd[t] = (i < n) ? deg[i] : 0;
    __syncthreads();
    for (int o = 1; o < 256; o <<= 1) {
        int u = (t >= o) ? sd[t - o] : 0;
        __syncthreads();
        sd[t] += u;
        __syncthreads();
    }
    if (i < n) offsets[i + 1] = bsums[blockIdx.x] + sd[t];
    if (i == 0) offsets[0] = 0;
}

// ---------------- CSR fill, chunked: LDS cursors + precomputed slice offsets (no global atomics) ----
__global__ __launch_bounds__(HTHREADS)
void fill_csr_kernel(const int* __restrict__ row, const int* __restrict__ col,
                     const float* __restrict__ dis, const int* __restrict__ offsets,
                     const int* __restrict__ part_col, int2* __restrict__ csr, int E) {
    __shared__ int cur[FCHUNK];
    int s = blockIdx.x;        // edge slice
    int c = blockIdx.y;        // node chunk
    int base = c * FCHUNK;
    int t = threadIdx.x;
    for (int i = t; i < FCHUNK; i += HTHREADS) cur[i] = 0;
    __syncthreads();
    int e0 = s * (E / NSLICE), e1 = e0 + E / NSLICE;
    for (int e = e0 + t; e < e1; e += HTHREADS) {
        int r = row[e], cc = col[e];
        unsigned lc = (unsigned)(cc - base);
        if (lc < FCHUNK) {
            int pos = atomicAdd(&cur[lc], 1);
            int idx = offsets[cc] + part_col[(size_t)s * N_PAD + cc] + pos;
            csr[idx] = make_int2(r, __float_as_int(dis[r] * dis[cc]));
        }
    }
}

// ---------------- x -> fp16 convert ----------------
__global__ void convert_x_kernel(const float* __restrict__ x, unsigned short* __restrict__ xhi,
                                 int n4) {
    int i = blockIdx.x * blockDim.x + threadIdx.x;
    if (i < n4) {
        float4 v = ((const float4*)x)[i];
        float r[4] = {v.x, v.y, v.z, v.w};
        ushort4 hs;
        unsigned short* hp = (unsigned short*)&hs;
        #pragma unroll
        for (int j = 0; j < 4; ++j) hp[j] = f2h_us(r[j]);
        ((ushort4*)xhi)[i] = hs;
    }
}

// ---------------- propagation (full-row fp16 gather, 8-deep MLP; hi-only output) ----------------
__global__ void prop_kernel(const unsigned short* __restrict__ hsrc,
                            const int* __restrict__ offsets,
                            const int2* __restrict__ csr,
                            unsigned short* __restrict__ Ohi, int n) {
    int node = blockIdx.x * 4 + (threadIdx.x >> 6);
    if (node >= n) return;
    int lane = threadIdx.x & 63;
    int half = lane >> 5;
    int cl   = lane & 31;           // 16B chunk id within the 512B row
    int beg = offsets[node], end = offsets[node + 1];
    float acc[8] = {0.f, 0.f, 0.f, 0.f, 0.f, 0.f, 0.f, 0.f};
    for (int i = beg; i < end; i += 16) {
        float w[8];
        int s[8];
        #pragma unroll
        for (int u = 0; u < 8; ++u) {
            int iu = i + 2 * u + half;
            int2 rec = csr[min(iu, end - 1)];
            w[u] = (iu < end) ? __int_as_float(rec.y) : 0.f;
            s[u] = rec.x;
        }
        u16x8 v[8];
        #pragma unroll
        for (int u = 0; u < 8; ++u)
            v[u] = *(const u16x8*)(hsrc + (size_t)s[u] * HID + cl * 8);
        #pragma unroll
        for (int u = 0; u < 8; ++u)
            #pragma unroll
            for (int j = 0; j < 8; ++j)
                acc[j] += w[u] * h2f((unsigned short)v[u][j]);
    }
    #pragma unroll
    for (int j = 0; j < 8; ++j) acc[j] += __shfl_xor(acc[j], 32);
    if (half == 0) {
        u16x8 ov;
        #pragma unroll
        for (int j = 0; j < 8; ++j) ov[j] = f2h_us(acc[j]);
        *(u16x8*)(Ohi + (size_t)node * HID + cl * 8) = ov;
    }
}

// ---------------- tiled transpose -> single fp16 plane: src[R][C] -> dst[C][R] ----------------
__global__ void transpose_half_kernel(const float* __restrict__ src,
                                      unsigned short* __restrict__ dhi, int R, int C) {
    __shared__ float tile[32][33];
    int c0 = blockIdx.x * 32, r0 = blockIdx.y * 32;
    int tx = threadIdx.x, ty = threadIdx.y;   // block (32, 8)
    #pragma unroll
    for (int i = 0; i < 32; i += 8) {
        int r = r0 + ty + i, c = c0 + tx;
        tile[ty + i][tx] = (r < R && c < C) ? src[(size_t)r * C + c] : 0.f;
    }
    __syncthreads();
    #pragma unroll
    for (int i = 0; i < 32; i += 8) {
        int c = c0 + ty + i, r = r0 + tx;
        if (c < C && r < R) dhi[(size_t)c * R + r] = f2h_us(tile[tx][ty + i]);
    }
}

// ---------------- MFMA GEMM (fp16, single-plane A): 256x128 tile, 8 waves, 2-phase dbuf ------
#define GBM 256
#define GBN 128
#define GBK 32

// ACT: relu; OUTMODE: 0 = fp32 C, 1 = fp16 C; NC: column blocks; STATS: fused BN colstats
template<int ACT, int OUTMODE, int NC, int STATS>
__global__ __launch_bounds__(512)
void mfma_gemm_kernel(const unsigned short* __restrict__ A0h,
                      const unsigned short* __restrict__ A1h,
                      const unsigned short* __restrict__ A2h,
                      const unsigned short* __restrict__ Wh,
                      const float* __restrict__ bvec,
                      float* __restrict__ C, unsigned short* __restrict__ Chi,
                      float* __restrict__ bn_sums, float* __restrict__ bn_sumsq,
                      int M, int K, int seg, int Kout) {
    // [buf][kgroup(4)][row][8 f16]: A 16KB/buf, B 8KB/buf -> 48KB total (3 blocks/CU)
    __shared__ __attribute__((aligned(16))) unsigned short As_hi[2][4 * GBM * 8];
    __shared__ __attribute__((aligned(16))) unsigned short Bs_hi[2][4 * GBN * 8];

    int tid  = threadIdx.x;
    int lane = tid & 63;
    int w    = tid >> 6;                   // wave id 0..7
    int wm   = w & 3, wn = w >> 2;         // 4x2 waves, 64x64 output each
    int kg   = lane >> 4, lr = lane & 15;  // fragment lane decomposition
    int kgq  = w & 3, hf = w >> 2;         // staging role: kgroup + half

    int bid = blockIdx.x, p, c;
    if (NC == 2) {
        p = ((bid >> 4) << 3) + (bid & 7);
        c = (bid >> 3) & 1;
        if (p >= N_PAD / GBM) return;      // grid padded to multiple of 16
    } else { p = bid; c = 0; }
    int bm = p * GBM, bn = c * GBN;

    f32x4 acc[4][4];
    #pragma unroll
    for (int i = 0; i < 4; ++i)
        #pragma unroll
        for (int j = 0; j < 4; ++j)
            acc[i][j] = (f32x4){0.f, 0.f, 0.f, 0.f};

    // stage: 2 A + 1 B gload_lds per wave
    auto STAGE = [&](int buf, int k0) {
        const unsigned short *Aph; int kl0;
        if (k0 < seg)          { Aph = A0h; kl0 = k0; }
        else if (k0 < 2 * seg) { Aph = A1h; kl0 = k0 - seg; }
        else                   { Aph = A2h; kl0 = k0 - 2 * seg; }
        size_t rA = (size_t)64 * seg;
        const unsigned short* a_h = Aph + (size_t)(bm + hf * 128 + lane) * seg + kl0 + kgq * 8;
        gload_lds16(a_h,      &As_hi[buf][(kgq * GBM + hf * 128)      * 8]);
        gload_lds16(a_h + rA, &As_hi[buf][(kgq * GBM + hf * 128 + 64) * 8]);
        const unsigned short* b_h = Wh + (size_t)(bn + hf * 64 + lane) * K + k0 + kgq * 8;
        gload_lds16(b_h,      &Bs_hi[buf][(kgq * GBN + hf * 64)       * 8]);
    };

    int nt = K / GBK;
    STAGE(0, 0);
    asm volatile("s_waitcnt vmcnt(0)" ::: "memory");
    __builtin_amdgcn_s_barrier();
    __builtin_amdgcn_sched_barrier(0);

    for (int t = 0; t < nt; ++t) {
        int cur = t & 1;
        if (t + 1 < nt) STAGE(cur ^ 1, (t + 1) * GBK);   // overlaps this step's compute

        int abase = (kg * GBM + wm * 64 + lr) * 8;
        int bbase = (kg * GBN + wn * 64 + lr) * 8;
        f16x8 ah[4], bh[4];
        #pragma unroll
        for (int mf = 0; mf < 4; ++mf)
            ah[mf] = *(const f16x8*)&As_hi[cur][abase + mf * 16 * 8];
        #pragma unroll
        for (int nf = 0; nf < 4; ++nf)
            bh[nf] = *(const f16x8*)&Bs_hi[cur][bbase + nf * 16 * 8];
        #pragma unroll
        for (int mf = 0; mf < 4; ++mf)
            #pragma unroll
            for (int nf = 0; nf < 4; ++nf)
                acc[mf][nf] = __builtin_amdgcn_mfma_f32_16x16x32_f16(ah[mf], bh[nf], acc[mf][nf], 0, 0, 0);

        asm volatile("s_waitcnt vmcnt(0)" ::: "memory");  // next tile landed
        __builtin_amdgcn_s_barrier();                     // all waves done reading buf cur
        __builtin_amdgcn_sched_barrier(0);
    }

    // ---- epilogue: C/D layout col = lane&15, row = (lane>>4)*4 + reg ----
    #pragma unroll
    for (int nf = 0; nf < 4; ++nf) {
        int col = bn + wn * 64 + nf * 16 + lr;
        if (col >= Kout) continue;
        float bv = bvec[col];
        float s1 = 0.f, s2 = 0.f;
        #pragma unroll
        for (int mf = 0; mf < 4; ++mf) {
            #pragma unroll
            for (int i = 0; i < 4; ++i) {
                int rw = bm + wm * 64 + mf * 16 + kg * 4 + i;
                if (rw < M) {
                    float v = acc[mf][nf][i] + bv;
                    if (ACT == 1) v = fmaxf(v, 0.f);
                    if (STATS) { s1 += v; s2 += v * v; }
                    if (OUTMODE == 0) {
                        C[(size_t)rw * Kout + col] = v;
                    } else {
                        Chi[(size_t)rw * Kout + col] = f2h_us(v);
                    }
                }
            }
        }
        if (STATS) {
            s1 += __shfl_xor(s1, 16); s1 += __shfl_xor(s1, 32);
            s2 += __shfl_xor(s2, 16); s2 += __shfl_xor(s2, 32);
            if (kg == 0) {
                atomicAdd(&bn_sums[col], s1);
                atomicAdd(&bn_sumsq[col], s2);
            }
        }
    }
}

// bnrelu: reads fp16 y, writes fp16 h
__global__ void bnrelu_kernel(const unsigned short* __restrict__ y, const float* __restrict__ sums,
                              const float* __restrict__ sumsq, const float* __restrict__ g,
                              const float* __restrict__ beta,
                              unsigned short* __restrict__ Hhi, int M) {
    int idx = blockIdx.x * blockDim.x + threadIdx.x;   // group of 4 channels
    if (idx < M * HID / 4) {
        int col0 = (idx * 4) & (HID - 1);
        ushort4 v = ((const ushort4*)y)[idx];
        unsigned short* vp = (unsigned short*)&v;
        float invM = 1.0f / (float)M;
        ushort4 hs;
        unsigned short* hp = (unsigned short*)&hs;
        #pragma unroll
        for (int j = 0; j < 4; ++j) {
            int col = col0 + j;
            float mean = sums[col] * invM;
            float var  = fmaxf(sumsq[col] * invM - mean * mean, 0.f);
            float o = (h2f(vp[j]) - mean) * rsqrtf(var + BN_EPS) * g[col] + beta[col];
            o = fmaxf(o, 0.f);
            hp[j] = f2h_us(o);
        }
        ((ushort4*)Hhi)[idx] = hs;
    }
}

extern "C" void kernel_launch(void* const* d_in, const int* in_sizes, int n_in,
                              void* d_out, int out_size, void* d_ws, size_t ws_size,
                              hipStream_t stream) {
    const float* x      = (const float*)d_in[0];
    const int*   ei     = (const int*)d_in[1];
    const float* W_feat = (const float*)d_in[2];
    const float* b_feat = (const float*)d_in[3];
    const float* W0     = (const float*)d_in[4];
    const float* b0     = (const float*)d_in[5];
    const float* g0     = (const float*)d_in[6];
    const float* beta0  = (const float*)d_in[7];
    const float* W1     = (const float*)d_in[8];
    const float* b1     = (const float*)d_in[9];
    const float* g1     = (const float*)d_in[10];
    const float* beta1  = (const float*)d_in[11];
    const float* Wc     = (const float*)d_in[12];
    const float* bc     = (const float*)d_in[13];
    float* out = (float*)d_out;

    const int N = N_NODES, E = N_EDGES;
    const int* row = ei;
    const int* col = ei + E;

    // workspace carve-up
    char* ws = (char*)d_ws;
    size_t off = 0;
    auto alloc = [&](size_t bytes) -> void* {
        void* p = ws + off;
        off = (off + bytes + 255) & ~(size_t)255;
        return p;
    };
    int*   deg_col  = (int*)  alloc(N * 4);
    int*   offsets  = (int*)  alloc((N + 1) * 4);
    int*   bsums    = (int*)  alloc(256 * 4);
    float* dis      = (float*)alloc(N * 4);
    int*   part_row = (int*)  alloc((size_t)NSLICE * N_PAD * 4);
    int*   part_col = (int*)  alloc((size_t)NSLICE * N_PAD * 4);
    int2*  csr      = (int2*) alloc((size_t)E * 8);
    unsigned short* x_hi    = (unsigned short*)alloc((size_t)N_PAD * IN_CH * 2);
    unsigned short* h_hi    = (unsigned short*)alloc((size_t)N_PAD * HID * 2);
    unsigned short* agg1_hi = (unsigned short*)alloc((size_t)N_PAD * HID * 2);
    // lifetime aliasing: x_hi (2 * N_PAD*HID ushorts) is dead after the feat GEMM
    unsigned short* agg2_hi = x_hi;                          // first half
    unsigned short* y_h     = x_hi + (size_t)N_PAD * HID;    // second half
    float* sums     = (float*)alloc(HID * 4);
    float* sumsq    = (float*)alloc(HID * 4);
    unsigned short* WTf_hi = (unsigned short*)alloc((size_t)HID * IN_CH * 2);
    unsigned short* WT0_hi = (unsigned short*)alloc((size_t)HID * 3 * HID * 2);
    unsigned short* WT1_hi = (unsigned short*)alloc((size_t)HID * 3 * HID * 2);
    unsigned short* WTc_hi = (unsigned short*)alloc((size_t)128 * HID * 2);   // 40 rows padded to 128

    hipMemsetAsync(WTc_hi, 0, (size_t)128 * HID * 2, stream);

    // operand pre-converts (independent of CSR build)
    convert_x_kernel<<<(N * IN_CH / 4 + 255) / 256, 256, 0, stream>>>(x, x_hi, N * IN_CH / 4);
    dim3 tb(32, 8);
    transpose_half_kernel<<<dim3(HID / 32, IN_CH / 32), tb, 0, stream>>>(W_feat, WTf_hi, IN_CH, HID);
    transpose_half_kernel<<<dim3(HID / 32, 3 * HID / 32), tb, 0, stream>>>(W0, WT0_hi, 3 * HID, HID);
    transpose_half_kernel<<<dim3(HID / 32, 3 * HID / 32), tb, 0, stream>>>(W1, WT1_hi, 3 * HID, HID);
    transpose_half_kernel<<<dim3((OUT_CH + 31) / 32, HID / 32), tb, 0, stream>>>(Wc, WTc_hi, HID, OUT_CH);

    // degree histograms (LDS-privatized, atomic-free globally)
    hist_kernel<<<dim3(NSLICE, NCHUNK), HTHREADS, 0, stream>>>(row, col, part_row, part_col, E);

    const int NB_SCAN = (N + 255) / 256;   // 196
    merge_scan1_kernel<<<NB_SCAN, 256, 0, stream>>>(part_row, part_col, dis, deg_col, bsums, N);
    scan2_kernel<<<1, 256, 0, stream>>>(bsums, NB_SCAN);
    scan3_kernel<<<NB_SCAN, 256, 0, stream>>>(deg_col, bsums, offsets, N);
    // chunked fill: LDS cursors + per-(slice,node) offsets from hist prefix
    fill_csr_kernel<<<dim3(NSLICE, FNCHUNK), HTHREADS, 0, stream>>>(row, col, dis, offsets,
                                                                    part_col, csr, E);

    // NC=2 grids: 196 panels x 2 col-blocks, swizzle needs grid multiple of 16 -> 400 (guarded)
    const int G2 = 400;
    // h = relu(x @ W_feat + b_feat) -> fp16
    mfma_gemm_kernel<1, 1, 2, 0><<<G2, 512, 0, stream>>>(
        x_hi, nullptr, nullptr, WTf_hi, b_feat,
        nullptr, h_hi, nullptr, nullptr, N, IN_CH, IN_CH, HID);

    const unsigned short* WThs[2] = {WT0_hi, WT1_hi};
    const float* bs[2]    = {b0, b1};
    const float* gs[2]    = {g0, g1};
    const float* betas[2] = {beta0, beta1};
    int prop_grid = (N + 3) / 4;
    for (int layer = 0; layer < 2; ++layer) {
        prop_kernel<<<prop_grid, 256, 0, stream>>>(h_hi, offsets, csr, agg1_hi, N);
        prop_kernel<<<prop_grid, 256, 0, stream>>>(agg1_hi, offsets, csr, agg2_hi, N);
        hipMemsetAsync(sums, 0, HID * 4, stream);
        hipMemsetAsync(sumsq, 0, HID * 4, stream);
        mfma_gemm_kernel<0, 1, 2, 1><<<G2, 512, 0, stream>>>(
            h_hi, agg1_hi, agg2_hi, WThs[layer], bs[layer],
            nullptr, y_h, sums, sumsq, N, 3 * HID, HID, HID);
        bnrelu_kernel<<<(N * HID / 4 + 255) / 256, 256, 0, stream>>>(y_h, sums, sumsq, gs[layer],
                                                                     betas[layer], h_hi, N);
    }

    mfma_gemm_kernel<0, 0, 1, 0><<<N_PAD / GBM, 512, 0, stream>>>(
        h_hi, nullptr, nullptr, WTc_hi, bc,
        out, nullptr, nullptr, nullptr, N, HID, HID, OUT_CH);
}